// Round 1
// baseline (3264.040 us; speedup 1.0000x reference)
//
#include <hip/hip_runtime.h>
#include <cfloat>
#include <cmath>

// ---------------------------------------------------------------------------
// GNN message passing, fp32 baseline.
// Pipeline per launch:
//   1. CSR build: histogram -> hierarchical exclusive scan -> scatter
//   2. prepare: per-node edge-weight stats -> reps[n,32]
//   3. 3x fused iteration kernel: gather-reduce (mean/max/min of neighbor reps)
//      + concat -> 128->256->128->32 MLP (tanh) + l2 normalize, ping-pong reps
//   4. readout: gather generator nodes -> 32->64->32->1 MLP
// ---------------------------------------------------------------------------

__global__ void k_hist(const int* __restrict__ dst, int* __restrict__ deg, int E) {
    int e = blockIdx.x * 256 + threadIdx.x;
    if (e < E) atomicAdd(&deg[dst[e]], 1);
}

__global__ void k_bsum(const int* __restrict__ deg, int* __restrict__ bsum, int n) {
    __shared__ int sh[1024];
    int t = threadIdx.x;
    int i = blockIdx.x * 1024 + t;
    sh[t] = (i < n) ? deg[i] : 0;
    __syncthreads();
    for (int s = 512; s > 0; s >>= 1) {
        if (t < s) sh[t] += sh[t + s];
        __syncthreads();
    }
    if (t == 0) bsum[blockIdx.x] = sh[0];
}

__global__ void k_scanb(const int* __restrict__ bsum, int* __restrict__ boff, int nb) {
    __shared__ int sh[128];
    int t = threadIdx.x;
    int v = (t < nb) ? bsum[t] : 0;
    sh[t] = v;
    __syncthreads();
    for (int s = 1; s < 128; s <<= 1) {
        int u = (t >= s) ? sh[t - s] : 0;
        __syncthreads();
        sh[t] += u;
        __syncthreads();
    }
    boff[t] = sh[t] - v;  // exclusive
}

__global__ void k_scanfinal(const int* __restrict__ deg, const int* __restrict__ boff,
                            int* __restrict__ row_start, int* __restrict__ cursor,
                            int n, int E) {
    __shared__ int sh[1024];
    int t = threadIdx.x;
    int i = blockIdx.x * 1024 + t;
    int v = (i < n) ? deg[i] : 0;
    sh[t] = v;
    __syncthreads();
    for (int s = 1; s < 1024; s <<= 1) {
        int u = (t >= s) ? sh[t - s] : 0;
        __syncthreads();
        sh[t] += u;
        __syncthreads();
    }
    int excl = sh[t] - v + boff[blockIdx.x];
    if (i < n) { row_start[i] = excl; cursor[i] = excl; }
    if (i == n) row_start[n] = E;
}

__global__ void k_scatter(const int* __restrict__ dst, const int* __restrict__ src,
                          int* __restrict__ cursor, int* __restrict__ snbr,
                          int* __restrict__ seid, int E) {
    int e = blockIdx.x * 256 + threadIdx.x;
    if (e < E) {
        int d = dst[e];
        int p = atomicAdd(&cursor[d], 1);
        snbr[p] = src[e];
        seid[p] = e;
    }
}

// prepare(): per-destination-node edge weight stats; reps = [x(8), mean(4),
// max(4), min(4), sum(4), 0(8)]
__global__ void k_prepare(const float* __restrict__ x, const float* __restrict__ ew,
                          const int* __restrict__ row_start, const int* __restrict__ seid,
                          float* __restrict__ reps, int n) {
    int v = blockIdx.x * 256 + threadIdx.x;
    if (v >= n) return;
    int s0 = row_start[v], s1 = row_start[v + 1];
    float4 s = {0.f, 0.f, 0.f, 0.f};
    float4 mx = {-INFINITY, -INFINITY, -INFINITY, -INFINITY};
    float4 mn = {INFINITY, INFINITY, INFINITY, INFINITY};
    const float4* ew4 = reinterpret_cast<const float4*>(ew);
    for (int e = s0; e < s1; ++e) {
        float4 w = ew4[seid[e]];
        s.x += w.x; s.y += w.y; s.z += w.z; s.w += w.w;
        mx.x = fmaxf(mx.x, w.x); mx.y = fmaxf(mx.y, w.y);
        mx.z = fmaxf(mx.z, w.z); mx.w = fmaxf(mx.w, w.w);
        mn.x = fminf(mn.x, w.x); mn.y = fminf(mn.y, w.y);
        mn.z = fminf(mn.z, w.z); mn.w = fminf(mn.w, w.w);
    }
    float cnt = fmaxf((float)(s1 - s0), 1.0f);
    // TF semantics: empty segment max -> -inf -> finfo.min (and min -> +max)
    mx.x = (isinf(mx.x) && mx.x < 0.f) ? -FLT_MAX : mx.x;
    mx.y = (isinf(mx.y) && mx.y < 0.f) ? -FLT_MAX : mx.y;
    mx.z = (isinf(mx.z) && mx.z < 0.f) ? -FLT_MAX : mx.z;
    mx.w = (isinf(mx.w) && mx.w < 0.f) ? -FLT_MAX : mx.w;
    mn.x = (isinf(mn.x) && mn.x > 0.f) ? FLT_MAX : mn.x;
    mn.y = (isinf(mn.y) && mn.y > 0.f) ? FLT_MAX : mn.y;
    mn.z = (isinf(mn.z) && mn.z > 0.f) ? FLT_MAX : mn.z;
    mn.w = (isinf(mn.w) && mn.w > 0.f) ? FLT_MAX : mn.w;
    float4 mean = {s.x / cnt, s.y / cnt, s.z / cnt, s.w / cnt};
    const float4* x4 = reinterpret_cast<const float4*>(x);
    float4* o = reinterpret_cast<float4*>(&reps[(size_t)v * 32]);
    float4 z = {0.f, 0.f, 0.f, 0.f};
    o[0] = x4[v * 2 + 0];
    o[1] = x4[v * 2 + 1];
    o[2] = mean;
    o[3] = mx;
    o[4] = mn;
    o[5] = s;
    o[6] = z;
    o[7] = z;
}

// One fused iteration: gather-reduce + 3-layer MLP + l2 normalize.
// Block = 256 threads, TILE = 32 nodes.
// LDS: bufA = 32x256 (h1, later h3 32x32), bufB = 32x128 (h_in, later h2).
__global__ __launch_bounds__(256) void k_iter(
    const float* __restrict__ reps_in, float* __restrict__ reps_out,
    const int* __restrict__ row_start, const int* __restrict__ snbr,
    const float* __restrict__ Wu1, const float* __restrict__ bu1,
    const float* __restrict__ Wu2, const float* __restrict__ bu2,
    const float* __restrict__ Wu3, const float* __restrict__ bu3,
    int n) {
    __shared__ float bufA[32 * 256];
    __shared__ float bufB[32 * 128];
    __shared__ float scl[32];
    const int tid = threadIdx.x;
    const int base = blockIdx.x * 32;

    // ---- gather-reduce phase: 8 groups of 32 lanes, 4 nodes per group ----
    {
        int grp = tid >> 5, lane = tid & 31;
        for (int i = grp; i < 32; i += 8) {
            int node = base + i;
            float r = 0.f, s = 0.f, mx = -INFINITY, mn = INFINITY;
            int d0 = 0, d1 = 0;
            if (node < n) {
                r = reps_in[(size_t)node * 32 + lane];
                d0 = row_start[node];
                d1 = row_start[node + 1];
                for (int e = d0; e < d1; ++e) {
                    int nbr = snbr[e];
                    float vv = reps_in[(size_t)nbr * 32 + lane];
                    s += vv;
                    mx = fmaxf(mx, vv);
                    mn = fminf(mn, vv);
                }
            }
            float cnt = fmaxf((float)(d1 - d0), 1.0f);
            mx = (isinf(mx) && mx < 0.f) ? -FLT_MAX : mx;
            mn = (isinf(mn) && mn > 0.f) ? FLT_MAX : mn;
            bufB[i * 128 + lane] = r;
            bufB[i * 128 + 32 + lane] = s / cnt;
            bufB[i * 128 + 64 + lane] = mx;
            bufB[i * 128 + 96 + lane] = mn;
        }
    }
    __syncthreads();

    // ---- layer 1: [32,128] @ [128,256], thread = output column ----
    {
        int j = tid;
        float acc[32];
#pragma unroll
        for (int i = 0; i < 32; ++i) acc[i] = 0.f;
        for (int k = 0; k < 128; k += 4) {
            float w0 = Wu1[(k + 0) * 256 + j];
            float w1 = Wu1[(k + 1) * 256 + j];
            float w2 = Wu1[(k + 2) * 256 + j];
            float w3 = Wu1[(k + 3) * 256 + j];
#pragma unroll
            for (int i = 0; i < 32; ++i) {
                const float4 hv = *reinterpret_cast<const float4*>(&bufB[i * 128 + k]);
                acc[i] = fmaf(hv.x, w0, fmaf(hv.y, w1, fmaf(hv.z, w2, fmaf(hv.w, w3, acc[i]))));
            }
        }
        float b = bu1[j];
#pragma unroll
        for (int i = 0; i < 32; ++i) bufA[i * 256 + j] = tanhf(acc[i] + b);
    }
    __syncthreads();

    // ---- layer 2: [32,256] @ [256,128]; 256 thr = 128 cols x 2 node halves ----
    {
        int col = tid & 127, half = tid >> 7;
        float acc[16];
#pragma unroll
        for (int i = 0; i < 16; ++i) acc[i] = 0.f;
        for (int k = 0; k < 256; k += 4) {
            float w0 = Wu2[(k + 0) * 128 + col];
            float w1 = Wu2[(k + 1) * 128 + col];
            float w2 = Wu2[(k + 2) * 128 + col];
            float w3 = Wu2[(k + 3) * 128 + col];
#pragma unroll
            for (int i = 0; i < 16; ++i) {
                const float4 hv = *reinterpret_cast<const float4*>(&bufA[(half * 16 + i) * 256 + k]);
                acc[i] = fmaf(hv.x, w0, fmaf(hv.y, w1, fmaf(hv.z, w2, fmaf(hv.w, w3, acc[i]))));
            }
        }
        float b = bu2[col];
#pragma unroll
        for (int i = 0; i < 16; ++i) bufB[(half * 16 + i) * 128 + col] = tanhf(acc[i] + b);
    }
    __syncthreads();

    // ---- layer 3: [32,128] @ [128,32]; 256 thr = 32 cols x 8 node groups ----
    {
        int col = tid & 31, grp = tid >> 5;
        float acc[4] = {0.f, 0.f, 0.f, 0.f};
        for (int k = 0; k < 128; k += 4) {
            float w0 = Wu3[(k + 0) * 32 + col];
            float w1 = Wu3[(k + 1) * 32 + col];
            float w2 = Wu3[(k + 2) * 32 + col];
            float w3 = Wu3[(k + 3) * 32 + col];
#pragma unroll
            for (int i = 0; i < 4; ++i) {
                const float4 hv = *reinterpret_cast<const float4*>(&bufB[(grp * 4 + i) * 128 + k]);
                acc[i] = fmaf(hv.x, w0, fmaf(hv.y, w1, fmaf(hv.z, w2, fmaf(hv.w, w3, acc[i]))));
            }
        }
        float b = bu3[col];
#pragma unroll
        for (int i = 0; i < 4; ++i) bufA[(grp * 4 + i) * 32 + col] = tanhf(acc[i] + b);
    }
    __syncthreads();

    // ---- l2 normalize: 8 lanes per node compute sumsq, shfl-reduce ----
    {
        int node = tid >> 3, dg = tid & 7;
        const float4 hv = *reinterpret_cast<const float4*>(&bufA[node * 32 + dg * 4]);
        float ss = hv.x * hv.x + hv.y * hv.y + hv.z * hv.z + hv.w * hv.w;
        ss += __shfl_xor(ss, 1);
        ss += __shfl_xor(ss, 2);
        ss += __shfl_xor(ss, 4);
        if (dg == 0) scl[node] = rsqrtf(fmaxf(ss, 1e-12f));
    }
    __syncthreads();
    {
        int node = tid >> 3, dg = tid & 7;
        int gnode = base + node;
        if (gnode < n) {
            const float4 hv = *reinterpret_cast<const float4*>(&bufA[node * 32 + dg * 4]);
            float sc = scl[node];
            float4 o = {hv.x * sc, hv.y * sc, hv.z * sc, hv.w * sc};
            *reinterpret_cast<float4*>(&reps_out[(size_t)gnode * 32 + dg * 4]) = o;
        }
    }
}

// readout: gather generator nodes (nan->0), 32->64->32->1 MLP
__global__ __launch_bounds__(256) void k_readout(
    const float* __restrict__ reps, const int* __restrict__ gen,
    const float* __restrict__ Wr1, const float* __restrict__ br1,
    const float* __restrict__ Wr2, const float* __restrict__ br2,
    const float* __restrict__ Wr3, const float* __restrict__ br3,
    float* __restrict__ out, int ngen) {
    __shared__ float sW1[32 * 64];
    __shared__ float sW2[64 * 32];
    __shared__ float sb1[64];
    __shared__ float sb2[32];
    __shared__ float sW3[32];
    __shared__ float sb3;
    int tid = threadIdx.x;
    for (int i = tid; i < 2048; i += 256) sW1[i] = Wr1[i];
    for (int i = tid; i < 2048; i += 256) sW2[i] = Wr2[i];
    if (tid < 64) sb1[tid] = br1[tid];
    if (tid < 32) sb2[tid] = br2[tid];
    if (tid < 32) sW3[tid] = Wr3[tid];
    if (tid == 0) sb3 = br3[0];
    __syncthreads();
    int ig = blockIdx.x * 256 + tid;
    if (ig >= ngen) return;
    int node = gen[ig];
    float g[32];
#pragma unroll
    for (int q = 0; q < 8; ++q) {
        float4 v = *reinterpret_cast<const float4*>(&reps[(size_t)node * 32 + q * 4]);
        g[q * 4 + 0] = (v.x != v.x) ? 0.f : v.x;
        g[q * 4 + 1] = (v.y != v.y) ? 0.f : v.y;
        g[q * 4 + 2] = (v.z != v.z) ? 0.f : v.z;
        g[q * 4 + 3] = (v.w != v.w) ? 0.f : v.w;
    }
    float a[64];
#pragma unroll
    for (int o = 0; o < 64; ++o) {
        float acc = sb1[o];
#pragma unroll
        for (int k = 0; k < 32; ++k) acc = fmaf(g[k], sW1[k * 64 + o], acc);
        a[o] = tanhf(acc);
    }
    float b[32];
#pragma unroll
    for (int o = 0; o < 32; ++o) {
        float acc = sb2[o];
#pragma unroll
        for (int k = 0; k < 64; ++k) acc = fmaf(a[k], sW2[k * 32 + o], acc);
        b[o] = tanhf(acc);
    }
    float acc = sb3;
#pragma unroll
    for (int k = 0; k < 32; ++k) acc = fmaf(b[k], sW3[k], acc);
    out[ig] = acc;
}

extern "C" void kernel_launch(void* const* d_in, const int* in_sizes, int n_in,
                              void* d_out, int out_size, void* d_ws, size_t ws_size,
                              hipStream_t stream) {
    const float* x   = (const float*)d_in[0];
    const float* ew  = (const float*)d_in[1];
    const float* Wu1 = (const float*)d_in[2];
    const float* bu1 = (const float*)d_in[3];
    const float* Wu2 = (const float*)d_in[4];
    const float* bu2 = (const float*)d_in[5];
    const float* Wu3 = (const float*)d_in[6];
    const float* bu3 = (const float*)d_in[7];
    const float* Wr1 = (const float*)d_in[8];
    const float* br1 = (const float*)d_in[9];
    const float* Wr2 = (const float*)d_in[10];
    const float* br2 = (const float*)d_in[11];
    const float* Wr3 = (const float*)d_in[12];
    const float* br3 = (const float*)d_in[13];
    const int* edges = (const int*)d_in[14];
    const int* gen   = (const int*)d_in[15];

    const int n    = in_sizes[0] / 8;
    const int E    = in_sizes[1] / 4;
    const int ngen = in_sizes[15];
    const int* dst = edges;        // node_idx (segment ids)
    const int* src = edges + E;    // nbr_idx (gather source)
    float* out = (float*)d_out;

    // workspace layout (256B aligned slabs)
    char* ws = (char*)d_ws;
    size_t off = 0;
    auto alloc = [&](size_t bytes) -> char* {
        char* p = ws + off;
        off = (off + bytes + 255) & ~(size_t)255;
        return p;
    };
    int* deg       = (int*)alloc((size_t)n * 4);
    int* row_start = (int*)alloc((size_t)(n + 1) * 4);
    int* cursor    = (int*)alloc((size_t)n * 4);
    int* bsum      = (int*)alloc(1024);
    int* boff      = (int*)alloc(1024);
    int* snbr      = (int*)alloc((size_t)E * 4);
    int* seid      = (int*)alloc((size_t)E * 4);
    float* repsA   = (float*)alloc((size_t)n * 32 * 4);
    float* repsB   = (float*)alloc((size_t)n * 32 * 4);

    hipMemsetAsync(deg, 0, (size_t)n * 4, stream);
    k_hist<<<(E + 255) / 256, 256, 0, stream>>>(dst, deg, E);
    int nb = (n + 1023) / 1024;
    k_bsum<<<nb, 1024, 0, stream>>>(deg, bsum, n);
    k_scanb<<<1, 128, 0, stream>>>(bsum, boff, nb);
    k_scanfinal<<<nb, 1024, 0, stream>>>(deg, boff, row_start, cursor, n, E);
    k_scatter<<<(E + 255) / 256, 256, 0, stream>>>(dst, src, cursor, snbr, seid, E);
    k_prepare<<<(n + 255) / 256, 256, 0, stream>>>(x, ew, row_start, seid, repsA, n);

    int ng = (n + 31) / 32;
    k_iter<<<ng, 256, 0, stream>>>(repsA, repsB, row_start, snbr, Wu1, bu1, Wu2, bu2, Wu3, bu3, n);
    k_iter<<<ng, 256, 0, stream>>>(repsB, repsA, row_start, snbr, Wu1, bu1, Wu2, bu2, Wu3, bu3, n);
    k_iter<<<ng, 256, 0, stream>>>(repsA, repsB, row_start, snbr, Wu1, bu1, Wu2, bu2, Wu3, bu3, n);

    k_readout<<<(ngen + 255) / 256, 256, 0, stream>>>(repsB, gen, Wr1, br1, Wr2, br2, Wr3, br3, out, ngen);
}

// Round 3
// 635.665 us; speedup vs baseline: 5.1348x; 5.1348x over previous
//
#include <hip/hip_runtime.h>
#include <cfloat>
#include <cmath>

// ---------------------------------------------------------------------------
// GNN message passing — fp16 MFMA version (round 3: fixed LDS staging index
// math — W1/W2/W3 chunk-per-row shifts were wrong in round 2 and W2 staging
// overflowed sW into sh1).
//   CSR build -> prepare (fp32 stats) -> 3x [gather->H fp16 ; fused MFMA MLP]
//   -> readout.
// MFMA trick: D = A*B with A = W^T stored [nout][k] and B = H stored [node][k]
// puts BOTH fragment loads on 16B-contiguous addresses (A rows / B rows).
// D frag: col = lane&15 = node, row = (lane>>4)*4+reg = nout  [guide §3].
// ---------------------------------------------------------------------------

typedef _Float16 half_t;
typedef _Float16 half8 __attribute__((ext_vector_type(8)));
typedef _Float16 half4_t __attribute__((ext_vector_type(4)));
typedef float f32x4 __attribute__((ext_vector_type(4)));

__device__ __forceinline__ float fast_tanh(float x) {
    // 1 - 2/(exp(2x)+1): exact saturation at +-1, no NaN for finite x
    return 1.0f - 2.0f / (1.0f + __expf(2.0f * x));
}

// ---------------- CSR build ----------------
__global__ void k_hist(const int* __restrict__ dst, int* __restrict__ deg, int E) {
    int e = blockIdx.x * 256 + threadIdx.x;
    if (e < E) atomicAdd(&deg[dst[e]], 1);
}

__global__ void k_bsum(const int* __restrict__ deg, int* __restrict__ bsum, int n) {
    __shared__ int sh[1024];
    int t = threadIdx.x;
    int i = blockIdx.x * 1024 + t;
    sh[t] = (i < n) ? deg[i] : 0;
    __syncthreads();
    for (int s = 512; s > 0; s >>= 1) {
        if (t < s) sh[t] += sh[t + s];
        __syncthreads();
    }
    if (t == 0) bsum[blockIdx.x] = sh[0];
}

__global__ void k_scanb(const int* __restrict__ bsum, int* __restrict__ boff, int nb) {
    __shared__ int sh[128];
    int t = threadIdx.x;
    int v = (t < nb) ? bsum[t] : 0;
    sh[t] = v;
    __syncthreads();
    for (int s = 1; s < 128; s <<= 1) {
        int u = (t >= s) ? sh[t - s] : 0;
        __syncthreads();
        sh[t] += u;
        __syncthreads();
    }
    boff[t] = sh[t] - v;  // exclusive
}

__global__ void k_scanfinal(const int* __restrict__ deg, const int* __restrict__ boff,
                            int* __restrict__ row_start, int* __restrict__ cursor,
                            int n, int E) {
    __shared__ int sh[1024];
    int t = threadIdx.x;
    int i = blockIdx.x * 1024 + t;
    int v = (i < n) ? deg[i] : 0;
    sh[t] = v;
    __syncthreads();
    for (int s = 1; s < 1024; s <<= 1) {
        int u = (t >= s) ? sh[t - s] : 0;
        __syncthreads();
        sh[t] += u;
        __syncthreads();
    }
    int excl = sh[t] - v + boff[blockIdx.x];
    if (i < n) { row_start[i] = excl; cursor[i] = excl; }
    if (i == n) row_start[n] = E;
}

__global__ void k_scatter(const int* __restrict__ dst, const int* __restrict__ src,
                          int* __restrict__ cursor, int* __restrict__ snbr,
                          int* __restrict__ seid, int E) {
    int e = blockIdx.x * 256 + threadIdx.x;
    if (e < E) {
        int d = dst[e];
        int p = atomicAdd(&cursor[d], 1);
        snbr[p] = src[e];
        seid[p] = e;
    }
}

// ---------------- prepare (fp32 stats -> reps[n,32]) ----------------
__global__ void k_prepare(const float* __restrict__ x, const float* __restrict__ ew,
                          const int* __restrict__ row_start, const int* __restrict__ seid,
                          float* __restrict__ reps, int n) {
    int v = blockIdx.x * 256 + threadIdx.x;
    if (v >= n) return;
    int s0 = row_start[v], s1 = row_start[v + 1];
    float4 s = {0.f, 0.f, 0.f, 0.f};
    float4 mx = {-INFINITY, -INFINITY, -INFINITY, -INFINITY};
    float4 mn = {INFINITY, INFINITY, INFINITY, INFINITY};
    const float4* ew4 = reinterpret_cast<const float4*>(ew);
    for (int e = s0; e < s1; ++e) {
        float4 w = ew4[seid[e]];
        s.x += w.x; s.y += w.y; s.z += w.z; s.w += w.w;
        mx.x = fmaxf(mx.x, w.x); mx.y = fmaxf(mx.y, w.y);
        mx.z = fmaxf(mx.z, w.z); mx.w = fmaxf(mx.w, w.w);
        mn.x = fminf(mn.x, w.x); mn.y = fminf(mn.y, w.y);
        mn.z = fminf(mn.z, w.z); mn.w = fminf(mn.w, w.w);
    }
    float cnt = fmaxf((float)(s1 - s0), 1.0f);
    if (s1 == s0) {
        mx = {-FLT_MAX, -FLT_MAX, -FLT_MAX, -FLT_MAX};
        mn = {FLT_MAX, FLT_MAX, FLT_MAX, FLT_MAX};
    }
    float4 mean = {s.x / cnt, s.y / cnt, s.z / cnt, s.w / cnt};
    const float4* x4 = reinterpret_cast<const float4*>(x);
    float4* o = reinterpret_cast<float4*>(&reps[(size_t)v * 32]);
    float4 z = {0.f, 0.f, 0.f, 0.f};
    o[0] = x4[v * 2 + 0];
    o[1] = x4[v * 2 + 1];
    o[2] = mean;
    o[3] = mx;
    o[4] = mn;
    o[5] = s;
    o[6] = z;
    o[7] = z;
}

// ---------------- weight prep: fp32 [k][n] -> fp16 [n][k] ----------------
__global__ void k_wprep(const float* __restrict__ Wu1, const float* __restrict__ Wu2,
                        const float* __restrict__ Wu3, half_t* __restrict__ Wt1,
                        half_t* __restrict__ Wt2, half_t* __restrict__ Wt3) {
    int i = blockIdx.x * 256 + threadIdx.x;
    if (i < 32768) {
        int nrow = i >> 7, k = i & 127;
        Wt1[i] = (half_t)Wu1[k * 256 + nrow];
    } else if (i < 65536) {
        int j = i - 32768;
        int nrow = j >> 8, k = j & 255;
        Wt2[j] = (half_t)Wu2[k * 128 + nrow];
    } else if (i < 69632) {
        int j = i - 65536;
        int nrow = j >> 7, k = j & 127;
        Wt3[j] = (half_t)Wu3[k * 32 + nrow];
    }
}

// ---------------- gather: reps fp32 -> H[node][128] fp16 ----------------
// 8 nodes per 256-thread block; 32 lanes per node (lane = feature).
// Clamp to +-60000 before fp16 cast: keeps the +-3.4e38 empty-segment
// sentinels finite in fp16 (tanh saturation semantics preserved).
__global__ __launch_bounds__(256) void k_gather(
    const float* __restrict__ reps, const int* __restrict__ row_start,
    const int* __restrict__ snbr, half_t* __restrict__ H, int n, int npad) {
    int grp = threadIdx.x >> 5, lane = threadIdx.x & 31;
    int node = blockIdx.x * 8 + grp;
    if (node >= npad) return;
    size_t hb = (size_t)node * 128;
    if (node >= n) {  // zero the pad rows so junk never feeds the MFMA
        H[hb + lane] = (half_t)0.f;
        H[hb + 32 + lane] = (half_t)0.f;
        H[hb + 64 + lane] = (half_t)0.f;
        H[hb + 96 + lane] = (half_t)0.f;
        return;
    }
    float r = reps[(size_t)node * 32 + lane];
    int d0 = row_start[node], d1 = row_start[node + 1];
    float s = 0.f, mx = -INFINITY, mn = INFINITY;
    for (int e0 = d0; e0 < d1; e0 += 32) {
        int m = d1 - e0; if (m > 32) m = 32;
        int idx = (e0 + lane < d1) ? snbr[e0 + lane] : 0;
        for (int j = 0; j < m; ++j) {
            int nbr = __shfl(idx, j, 32);
            float v = reps[(size_t)nbr * 32 + lane];
            s += v;
            mx = fmaxf(mx, v);
            mn = fminf(mn, v);
        }
    }
    float cnt = fmaxf((float)(d1 - d0), 1.f);
    if (d1 == d0) { mx = -FLT_MAX; mn = FLT_MAX; }
    float mean = s / cnt;
    auto cv = [](float v) -> half_t {
        return (half_t)fminf(fmaxf(v, -60000.f), 60000.f);
    };
    H[hb + lane]       = cv(r);
    H[hb + 32 + lane]  = cv(mean);
    H[hb + 64 + lane]  = cv(mx);
    H[hb + 96 + lane]  = cv(mn);
}

// ---------------- fused MLP: H -> tanh MLP x3 -> l2norm -> reps ----------------
// Block: 512 threads (8 waves), 128 nodes. LDS 142.5 KB -> 1 block/CU.
// Weight LDS rows padded +8 halfs (stride 272B/528B): row-to-row bank shift 4
// -> 16-lane frag reads are 2-way conflicts = free (m136).
#define MFMA16(a, b, c) __builtin_amdgcn_mfma_f32_16x16x32_f16((a), (b), (c), 0, 0, 0)

__global__ __launch_bounds__(512, 2) void k_mlp(
    const half_t* __restrict__ H,
    const half_t* __restrict__ Wt1, const half_t* __restrict__ Wt2,
    const half_t* __restrict__ Wt3,
    const float* __restrict__ bu1, const float* __restrict__ bu2,
    const float* __restrict__ bu3,
    float* __restrict__ reps_out, int n) {
    __shared__ half_t sW[34816];   // W1t[256][136] -> W2t[128][264] -> h2[128][136]
    __shared__ half_t sh1[33792];  // h1[128][264]
    __shared__ half_t sW3[4352];   // W3t[32][136]

    const int tid = threadIdx.x;
    const int w   = tid >> 6;        // wave 0..7
    const int l15 = tid & 15;
    const int lk  = (tid & 63) >> 4; // k-group 0..3
    const int node0 = blockIdx.x * 128;

    // ---- stage W3: 32 rows x 128 halfs = 16 chunks-of-8 per row ----
    {
        int row = tid >> 4, cc = tid & 15;   // 512 chunks total
        *(half8*)&sW3[row * 136 + cc * 8] = *(const half8*)&Wt3[row * 128 + cc * 8];
    }
    // ---- stage W1: 256 rows x 128 halfs = 16 chunks per row, 4096 chunks ----
#pragma unroll
    for (int i = 0; i < 8; ++i) {
        int c = tid + i * 512;
        int row = c >> 4, cc = c & 15;
        *(half8*)&sW[row * 136 + cc * 8] = *(const half8*)&Wt1[row * 128 + cc * 8];
    }
    __syncthreads();

    // ---- GEMM1: h1[node][256] = tanh(H @ W1 + b1); wave owns nout [w*32,w*32+32) ----
    {
        half8 a0[4], a1[4];
#pragma unroll
        for (int ks = 0; ks < 4; ++ks) {
            a0[ks] = *(const half8*)&sW[(w * 32 + l15) * 136 + ks * 32 + lk * 8];
            a1[ks] = *(const half8*)&sW[(w * 32 + 16 + l15) * 136 + ks * 32 + lk * 8];
        }
        f32x4 bv0 = *(const f32x4*)&bu1[w * 32 + lk * 4];
        f32x4 bv1 = *(const f32x4*)&bu1[w * 32 + 16 + lk * 4];
#pragma unroll
        for (int nt = 0; nt < 8; ++nt) {
            const half_t* hrow = &H[(size_t)(node0 + nt * 16 + l15) * 128 + lk * 8];
            half8 b0 = *(const half8*)&hrow[0];
            half8 b1 = *(const half8*)&hrow[32];
            half8 b2 = *(const half8*)&hrow[64];
            half8 b3 = *(const half8*)&hrow[96];
            f32x4 acc0 = {0.f, 0.f, 0.f, 0.f}, acc1 = {0.f, 0.f, 0.f, 0.f};
            acc0 = MFMA16(a0[0], b0, acc0);
            acc0 = MFMA16(a0[1], b1, acc0);
            acc0 = MFMA16(a0[2], b2, acc0);
            acc0 = MFMA16(a0[3], b3, acc0);
            acc1 = MFMA16(a1[0], b0, acc1);
            acc1 = MFMA16(a1[1], b1, acc1);
            acc1 = MFMA16(a1[2], b2, acc1);
            acc1 = MFMA16(a1[3], b3, acc1);
            int node = nt * 16 + l15;
            half4_t o0, o1;
#pragma unroll
            for (int r = 0; r < 4; ++r) {
                o0[r] = (half_t)fast_tanh(acc0[r] + bv0[r]);
                o1[r] = (half_t)fast_tanh(acc1[r] + bv1[r]);
            }
            *(half4_t*)&sh1[node * 264 + w * 32 + lk * 4] = o0;
            *(half4_t*)&sh1[node * 264 + w * 32 + 16 + lk * 4] = o1;
        }
    }
    __syncthreads();

    // ---- stage W2 over W1's LDS: 128 rows x 256 halfs = 32 chunks per row ----
#pragma unroll
    for (int i = 0; i < 8; ++i) {
        int c = tid + i * 512;
        int row = c >> 5, cc = c & 31;   // rows 0..127, 4096 chunks
        *(half8*)&sW[row * 264 + cc * 8] = *(const half8*)&Wt2[row * 256 + cc * 8];
    }
    __syncthreads();

    // ---- GEMM2: h2[node][128] = tanh(h1 @ W2 + b2); wave owns nout [w*16,w*16+16) ----
    half4_t h2r[8];
    {
        half8 a[8];
#pragma unroll
        for (int ks = 0; ks < 8; ++ks)
            a[ks] = *(const half8*)&sW[(w * 16 + l15) * 264 + ks * 32 + lk * 8];
        f32x4 bv = *(const f32x4*)&bu2[w * 16 + lk * 4];
#pragma unroll
        for (int nt = 0; nt < 8; ++nt) {
            f32x4 acc = {0.f, 0.f, 0.f, 0.f};
#pragma unroll
            for (int ks = 0; ks < 8; ++ks) {
                half8 b = *(const half8*)&sh1[(nt * 16 + l15) * 264 + ks * 32 + lk * 8];
                acc = MFMA16(a[ks], b, acc);
            }
#pragma unroll
            for (int r = 0; r < 4; ++r)
                h2r[nt][r] = (half_t)fast_tanh(acc[r] + bv[r]);
        }
    }
    __syncthreads();  // all waves done with W2 (sW) before overwrite
#pragma unroll
    for (int nt = 0; nt < 8; ++nt)
        *(half4_t*)&sW[(nt * 16 + l15) * 136 + w * 16 + lk * 4] = h2r[nt];
    __syncthreads();

    // ---- GEMM3 + l2norm: wave owns nodes [w*16,(w+1)*16) ----
    {
        half8 a0[4], a1[4], b[4];
#pragma unroll
        for (int ks = 0; ks < 4; ++ks) {
            a0[ks] = *(const half8*)&sW3[l15 * 136 + ks * 32 + lk * 8];
            a1[ks] = *(const half8*)&sW3[(16 + l15) * 136 + ks * 32 + lk * 8];
            b[ks]  = *(const half8*)&sW[(w * 16 + l15) * 136 + ks * 32 + lk * 8];
        }
        f32x4 acc0 = {0.f, 0.f, 0.f, 0.f}, acc1 = {0.f, 0.f, 0.f, 0.f};
#pragma unroll
        for (int ks = 0; ks < 4; ++ks) {
            acc0 = MFMA16(a0[ks], b[ks], acc0);
            acc1 = MFMA16(a1[ks], b[ks], acc1);
        }
        f32x4 bv0 = *(const f32x4*)&bu3[lk * 4];
        f32x4 bv1 = *(const f32x4*)&bu3[16 + lk * 4];
        float v0[4], v1[4];
        float ss = 0.f;
#pragma unroll
        for (int r = 0; r < 4; ++r) {
            v0[r] = fast_tanh(acc0[r] + bv0[r]);
            v1[r] = fast_tanh(acc1[r] + bv1[r]);
            ss += v0[r] * v0[r] + v1[r] * v1[r];
        }
        ss += __shfl_xor(ss, 16);
        ss += __shfl_xor(ss, 32);
        float sc = rsqrtf(fmaxf(ss, 1e-12f));
        int node = node0 + w * 16 + l15;
        if (node < n) {
            f32x4 o0 = {v0[0] * sc, v0[1] * sc, v0[2] * sc, v0[3] * sc};
            f32x4 o1 = {v1[0] * sc, v1[1] * sc, v1[2] * sc, v1[3] * sc};
            *(f32x4*)&reps_out[(size_t)node * 32 + lk * 4] = o0;
            *(f32x4*)&reps_out[(size_t)node * 32 + 16 + lk * 4] = o1;
        }
    }
}

// ---------------- readout: gather generators (nan->0), 32->64->32->1 ----------------
__global__ __launch_bounds__(256) void k_readout(
    const float* __restrict__ reps, const int* __restrict__ gen,
    const float* __restrict__ Wr1, const float* __restrict__ br1,
    const float* __restrict__ Wr2, const float* __restrict__ br2,
    const float* __restrict__ Wr3, const float* __restrict__ br3,
    float* __restrict__ out, int ngen) {
    __shared__ float sW1[32 * 64];
    __shared__ float sW2[64 * 32];
    __shared__ float sb1[64];
    __shared__ float sb2[32];
    __shared__ float sW3r[32];
    __shared__ float sb3;
    int tid = threadIdx.x;
    for (int i = tid; i < 2048; i += 256) sW1[i] = Wr1[i];
    for (int i = tid; i < 2048; i += 256) sW2[i] = Wr2[i];
    if (tid < 64) sb1[tid] = br1[tid];
    if (tid < 32) sb2[tid] = br2[tid];
    if (tid < 32) sW3r[tid] = Wr3[tid];
    if (tid == 0) sb3 = br3[0];
    __syncthreads();
    int ig = blockIdx.x * 256 + tid;
    if (ig >= ngen) return;
    int node = gen[ig];
    float g[32];
#pragma unroll
    for (int q = 0; q < 8; ++q) {
        float4 v = *reinterpret_cast<const float4*>(&reps[(size_t)node * 32 + q * 4]);
        g[q * 4 + 0] = (v.x != v.x) ? 0.f : v.x;
        g[q * 4 + 1] = (v.y != v.y) ? 0.f : v.y;
        g[q * 4 + 2] = (v.z != v.z) ? 0.f : v.z;
        g[q * 4 + 3] = (v.w != v.w) ? 0.f : v.w;
    }
    float a[64];
#pragma unroll
    for (int o = 0; o < 64; ++o) {
        float acc = sb1[o];
#pragma unroll
        for (int k = 0; k < 32; ++k) acc = fmaf(g[k], sW1[k * 64 + o], acc);
        a[o] = tanhf(acc);
    }
    float b[32];
#pragma unroll
    for (int o = 0; o < 32; ++o) {
        float acc = sb2[o];
#pragma unroll
        for (int k = 0; k < 64; ++k) acc = fmaf(a[k], sW2[k * 32 + o], acc);
        b[o] = tanhf(acc);
    }
    float acc = sb3;
#pragma unroll
    for (int k = 0; k < 32; ++k) acc = fmaf(b[k], sW3r[k], acc);
    out[ig] = acc;
}

extern "C" void kernel_launch(void* const* d_in, const int* in_sizes, int n_in,
                              void* d_out, int out_size, void* d_ws, size_t ws_size,
                              hipStream_t stream) {
    const float* x   = (const float*)d_in[0];
    const float* ew  = (const float*)d_in[1];
    const float* Wu1 = (const float*)d_in[2];
    const float* bu1 = (const float*)d_in[3];
    const float* Wu2 = (const float*)d_in[4];
    const float* bu2 = (const float*)d_in[5];
    const float* Wu3 = (const float*)d_in[6];
    const float* bu3 = (const float*)d_in[7];
    const float* Wr1 = (const float*)d_in[8];
    const float* br1 = (const float*)d_in[9];
    const float* Wr2 = (const float*)d_in[10];
    const float* br2 = (const float*)d_in[11];
    const float* Wr3 = (const float*)d_in[12];
    const float* br3 = (const float*)d_in[13];
    const int* edges = (const int*)d_in[14];
    const int* gen   = (const int*)d_in[15];

    const int n    = in_sizes[0] / 8;
    const int E    = in_sizes[1] / 4;
    const int ngen = in_sizes[15];
    const int* dst = edges;      // node_idx (segment ids)
    const int* src = edges + E;  // nbr_idx (gather source)
    float* out = (float*)d_out;

    const int nblk = (n + 127) / 128;
    const int npad = nblk * 128;

    // workspace layout (256B aligned slabs)
    char* ws = (char*)d_ws;
    size_t off = 0;
    auto alloc = [&](size_t bytes) -> char* {
        char* p = ws + off;
        off = (off + bytes + 255) & ~(size_t)255;
        return p;
    };
    int* deg       = (int*)alloc((size_t)n * 4);
    int* row_start = (int*)alloc((size_t)(n + 1) * 4);
    int* cursor    = (int*)alloc((size_t)n * 4);
    int* bsum      = (int*)alloc(1024);
    int* boff      = (int*)alloc(1024);
    int* snbr      = (int*)alloc((size_t)E * 4);
    // union: seid (CSR phase only) / H fp16 (iteration phase only)
    size_t useid = (size_t)E * 4;
    size_t uH    = (size_t)npad * 128 * 2;
    char* ubuf   = alloc(useid > uH ? useid : uH);
    int* seid    = (int*)ubuf;
    half_t* Hbuf = (half_t*)ubuf;
    float* repsA = (float*)alloc((size_t)npad * 32 * 4);
    float* repsB = (float*)alloc((size_t)npad * 32 * 4);
    half_t* Wt1  = (half_t*)alloc(32768 * 2);
    half_t* Wt2  = (half_t*)alloc(32768 * 2);
    half_t* Wt3  = (half_t*)alloc(4096 * 2);

    k_wprep<<<272, 256, 0, stream>>>(Wu1, Wu2, Wu3, Wt1, Wt2, Wt3);

    hipMemsetAsync(deg, 0, (size_t)n * 4, stream);
    k_hist<<<(E + 255) / 256, 256, 0, stream>>>(dst, deg, E);
    int nb = (n + 1023) / 1024;
    k_bsum<<<nb, 1024, 0, stream>>>(deg, bsum, n);
    k_scanb<<<1, 128, 0, stream>>>(bsum, boff, nb);
    k_scanfinal<<<nb, 1024, 0, stream>>>(deg, boff, row_start, cursor, n, E);
    k_scatter<<<(E + 255) / 256, 256, 0, stream>>>(dst, src, cursor, snbr, seid, E);
    k_prepare<<<(n + 255) / 256, 256, 0, stream>>>(x, ew, row_start, seid, repsA, n);

    float* cur = repsA;
    float* nxt = repsB;
    for (int it = 0; it < 3; ++it) {
        k_gather<<<npad / 8, 256, 0, stream>>>(cur, row_start, snbr, Hbuf, n, npad);
        k_mlp<<<nblk, 512, 0, stream>>>(Hbuf, Wt1, Wt2, Wt3, bu1, bu2, bu3, nxt, n);
        float* t = cur; cur = nxt; nxt = t;
    }

    k_readout<<<(ngen + 255) / 256, 256, 0, stream>>>(cur, gen, Wr1, br1, Wr2, br2,
                                                      Wr3, br3, out, ngen);
}

// Round 4
// 606.726 us; speedup vs baseline: 5.3798x; 1.0477x over previous
//
#include <hip/hip_runtime.h>
#include <cfloat>
#include <cmath>

// ---------------------------------------------------------------------------
// GNN message passing — fp16 MFMA version, round 4.
//  R4 changes (theory-first):
//   1. k_scatter writes ONE int2 {src,eid} (8B) instead of two 4B stores to
//      separate arrays -> halves dirtied 64B lines (WRITE_SIZE 153->~85MB).
//   2. k_gather: 4-wide unrolled neighbor loop -> breaks the serial
//      shfl->load->accum latency chain (4 independent row loads in flight).
//   3. k_mlp: weight LDS staging removed (fragments are loaded once per wave
//      into registers and reused across node tiles -> LDS round-trip was pure
//      overhead). 64 nodes/block, LDS = 34KB (h1 only, h2 overlaid) -> 2+
//      blocks/CU instead of 1.
// MFMA mapping (verified r3): D=A*B, A=W^T[nout][k], B=H[node][k]; both
// fragments 16B-contiguous. D: col=lane&15=node, row=(lane>>4)*4+reg=nout.
// ---------------------------------------------------------------------------

typedef _Float16 half_t;
typedef _Float16 half8 __attribute__((ext_vector_type(8)));
typedef _Float16 half4_t __attribute__((ext_vector_type(4)));
typedef float f32x4 __attribute__((ext_vector_type(4)));

__device__ __forceinline__ float fast_tanh(float x) {
    return 1.0f - 2.0f / (1.0f + __expf(2.0f * x));
}

// ---------------- CSR build ----------------
__global__ void k_hist(const int* __restrict__ dst, int* __restrict__ deg, int E) {
    int e = blockIdx.x * 256 + threadIdx.x;
    if (e < E) atomicAdd(&deg[dst[e]], 1);
}

__global__ void k_bsum(const int* __restrict__ deg, int* __restrict__ bsum, int n) {
    __shared__ int sh[1024];
    int t = threadIdx.x;
    int i = blockIdx.x * 1024 + t;
    sh[t] = (i < n) ? deg[i] : 0;
    __syncthreads();
    for (int s = 512; s > 0; s >>= 1) {
        if (t < s) sh[t] += sh[t + s];
        __syncthreads();
    }
    if (t == 0) bsum[blockIdx.x] = sh[0];
}

__global__ void k_scanb(const int* __restrict__ bsum, int* __restrict__ boff, int nb) {
    __shared__ int sh[128];
    int t = threadIdx.x;
    int v = (t < nb) ? bsum[t] : 0;
    sh[t] = v;
    __syncthreads();
    for (int s = 1; s < 128; s <<= 1) {
        int u = (t >= s) ? sh[t - s] : 0;
        __syncthreads();
        sh[t] += u;
        __syncthreads();
    }
    boff[t] = sh[t] - v;  // exclusive
}

__global__ void k_scanfinal(const int* __restrict__ deg, const int* __restrict__ boff,
                            int* __restrict__ row_start, int* __restrict__ cursor,
                            int n, int E) {
    __shared__ int sh[1024];
    int t = threadIdx.x;
    int i = blockIdx.x * 1024 + t;
    int v = (i < n) ? deg[i] : 0;
    sh[t] = v;
    __syncthreads();
    for (int s = 1; s < 1024; s <<= 1) {
        int u = (t >= s) ? sh[t - s] : 0;
        __syncthreads();
        sh[t] += u;
        __syncthreads();
    }
    int excl = sh[t] - v + boff[blockIdx.x];
    if (i < n) { row_start[i] = excl; cursor[i] = excl; }
    if (i == n) row_start[n] = E;
}

__global__ void k_scatter(const int* __restrict__ dst, const int* __restrict__ src,
                          int* __restrict__ cursor, int2* __restrict__ pairs, int E) {
    int e = blockIdx.x * 256 + threadIdx.x;
    if (e < E) {
        int d = dst[e];
        int p = atomicAdd(&cursor[d], 1);
        pairs[p] = make_int2(src[e], e);   // one 8B line-touch instead of two 4B
    }
}

// ---------------- prepare (fp32 stats -> reps[n,32]) ----------------
__global__ void k_prepare(const float* __restrict__ x, const float* __restrict__ ew,
                          const int* __restrict__ row_start, const int2* __restrict__ pairs,
                          float* __restrict__ reps, int n) {
    int v = blockIdx.x * 256 + threadIdx.x;
    if (v >= n) return;
    int s0 = row_start[v], s1 = row_start[v + 1];
    float4 s = {0.f, 0.f, 0.f, 0.f};
    float4 mx = {-INFINITY, -INFINITY, -INFINITY, -INFINITY};
    float4 mn = {INFINITY, INFINITY, INFINITY, INFINITY};
    const float4* ew4 = reinterpret_cast<const float4*>(ew);
    for (int e = s0; e < s1; ++e) {
        float4 w = ew4[pairs[e].y];
        s.x += w.x; s.y += w.y; s.z += w.z; s.w += w.w;
        mx.x = fmaxf(mx.x, w.x); mx.y = fmaxf(mx.y, w.y);
        mx.z = fmaxf(mx.z, w.z); mx.w = fmaxf(mx.w, w.w);
        mn.x = fminf(mn.x, w.x); mn.y = fminf(mn.y, w.y);
        mn.z = fminf(mn.z, w.z); mn.w = fminf(mn.w, w.w);
    }
    float cnt = fmaxf((float)(s1 - s0), 1.0f);
    if (s1 == s0) {
        mx = {-FLT_MAX, -FLT_MAX, -FLT_MAX, -FLT_MAX};
        mn = {FLT_MAX, FLT_MAX, FLT_MAX, FLT_MAX};
    }
    float4 mean = {s.x / cnt, s.y / cnt, s.z / cnt, s.w / cnt};
    const float4* x4 = reinterpret_cast<const float4*>(x);
    float4* o = reinterpret_cast<float4*>(&reps[(size_t)v * 32]);
    float4 z = {0.f, 0.f, 0.f, 0.f};
    o[0] = x4[v * 2 + 0];
    o[1] = x4[v * 2 + 1];
    o[2] = mean;
    o[3] = mx;
    o[4] = mn;
    o[5] = s;
    o[6] = z;
    o[7] = z;
}

// ---------------- weight prep: fp32 [k][n] -> fp16 [n][k] ----------------
__global__ void k_wprep(const float* __restrict__ Wu1, const float* __restrict__ Wu2,
                        const float* __restrict__ Wu3, half_t* __restrict__ Wt1,
                        half_t* __restrict__ Wt2, half_t* __restrict__ Wt3) {
    int i = blockIdx.x * 256 + threadIdx.x;
    if (i < 32768) {
        int nrow = i >> 7, k = i & 127;
        Wt1[i] = (half_t)Wu1[k * 256 + nrow];
    } else if (i < 65536) {
        int j = i - 32768;
        int nrow = j >> 8, k = j & 255;
        Wt2[j] = (half_t)Wu2[k * 128 + nrow];
    } else if (i < 69632) {
        int j = i - 65536;
        int nrow = j >> 7, k = j & 127;
        Wt3[j] = (half_t)Wu3[k * 32 + nrow];
    }
}

// ---------------- gather: reps fp32 -> H[node][128] fp16 ----------------
// 8 nodes per 256-thread block; 32 lanes per node (lane = feature).
// 4-wide unrolled neighbor loop: 4 independent 128B row loads in flight.
__global__ __launch_bounds__(256) void k_gather(
    const float* __restrict__ reps, const int* __restrict__ row_start,
    const int2* __restrict__ pairs, half_t* __restrict__ H, int n, int npad) {
    int grp = threadIdx.x >> 5, lane = threadIdx.x & 31;
    int node = blockIdx.x * 8 + grp;
    if (node >= npad) return;
    size_t hb = (size_t)node * 128;
    if (node >= n) {  // zero the pad rows so junk never feeds the MFMA
        H[hb + lane] = (half_t)0.f;
        H[hb + 32 + lane] = (half_t)0.f;
        H[hb + 64 + lane] = (half_t)0.f;
        H[hb + 96 + lane] = (half_t)0.f;
        return;
    }
    float r = reps[(size_t)node * 32 + lane];
    int d0 = row_start[node], d1 = row_start[node + 1];
    float s = 0.f, mx = -INFINITY, mn = INFINITY;
    for (int e0 = d0; e0 < d1; e0 += 32) {
        int m = d1 - e0; if (m > 32) m = 32;
        int idx = (e0 + lane < d1) ? pairs[e0 + lane].x : 0;
        int j = 0;
        for (; j + 4 <= m; j += 4) {
            int n0 = __shfl(idx, j, 32);
            int n1 = __shfl(idx, j + 1, 32);
            int n2 = __shfl(idx, j + 2, 32);
            int n3 = __shfl(idx, j + 3, 32);
            float v0 = reps[(size_t)n0 * 32 + lane];
            float v1 = reps[(size_t)n1 * 32 + lane];
            float v2 = reps[(size_t)n2 * 32 + lane];
            float v3 = reps[(size_t)n3 * 32 + lane];
            s += (v0 + v1) + (v2 + v3);
            mx = fmaxf(mx, fmaxf(fmaxf(v0, v1), fmaxf(v2, v3)));
            mn = fminf(mn, fminf(fminf(v0, v1), fminf(v2, v3)));
        }
        for (; j < m; ++j) {
            int nb = __shfl(idx, j, 32);
            float v = reps[(size_t)nb * 32 + lane];
            s += v;
            mx = fmaxf(mx, v);
            mn = fminf(mn, v);
        }
    }
    float cnt = fmaxf((float)(d1 - d0), 1.f);
    if (d1 == d0) { mx = -FLT_MAX; mn = FLT_MAX; }
    float mean = s / cnt;
    auto cv = [](float v) -> half_t {
        return (half_t)fminf(fmaxf(v, -60000.f), 60000.f);
    };
    H[hb + lane]       = cv(r);
    H[hb + 32 + lane]  = cv(mean);
    H[hb + 64 + lane]  = cv(mx);
    H[hb + 96 + lane]  = cv(mn);
}

// ---------------- fused MLP: H -> tanh MLP x3 -> l2norm -> reps ----------------
// 512 threads (8 waves), 64 nodes/block. Weight fragments load straight from
// global into registers (each is reused across all node tiles — no LDS stage).
// LDS: sh1[64][264] fp16 = 33.8KB (h1; h2[64][136] overlaid after barrier).
#define MFMA16(a, b, c) __builtin_amdgcn_mfma_f32_16x16x32_f16((a), (b), (c), 0, 0, 0)

__global__ __launch_bounds__(512, 4) void k_mlp(
    const half_t* __restrict__ H,
    const half_t* __restrict__ Wt1, const half_t* __restrict__ Wt2,
    const half_t* __restrict__ Wt3,
    const float* __restrict__ bu1, const float* __restrict__ bu2,
    const float* __restrict__ bu3,
    float* __restrict__ reps_out, int n) {
    __shared__ half_t sh1[64 * 264];   // h1[64][264]; later h2[64][136]

    const int tid = threadIdx.x;
    const int w   = tid >> 6;          // wave 0..7
    const int l15 = tid & 15;
    const int lk  = (tid & 63) >> 4;   // k-group 0..3
    const int node0 = blockIdx.x * 64;

    // ---- GEMM1: h1[node][256] = tanh(H @ W1 + b1); wave owns nout [w*32,w*32+32) ----
    {
        half8 a0[4], a1[4];
#pragma unroll
        for (int ks = 0; ks < 4; ++ks) {
            a0[ks] = *(const half8*)&Wt1[(w * 32 + l15) * 128 + ks * 32 + lk * 8];
            a1[ks] = *(const half8*)&Wt1[(w * 32 + 16 + l15) * 128 + ks * 32 + lk * 8];
        }
        f32x4 bv0 = *(const f32x4*)&bu1[w * 32 + lk * 4];
        f32x4 bv1 = *(const f32x4*)&bu1[w * 32 + 16 + lk * 4];
#pragma unroll
        for (int nt = 0; nt < 4; ++nt) {
            const half_t* hrow = &H[(size_t)(node0 + nt * 16 + l15) * 128 + lk * 8];
            half8 b0 = *(const half8*)&hrow[0];
            half8 b1 = *(const half8*)&hrow[32];
            half8 b2 = *(const half8*)&hrow[64];
            half8 b3 = *(const half8*)&hrow[96];
            f32x4 acc0 = {0.f, 0.f, 0.f, 0.f}, acc1 = {0.f, 0.f, 0.f, 0.f};
            acc0 = MFMA16(a0[0], b0, acc0);
            acc0 = MFMA16(a0[1], b1, acc0);
            acc0 = MFMA16(a0[2], b2, acc0);
            acc0 = MFMA16(a0[3], b3, acc0);
            acc1 = MFMA16(a1[0], b0, acc1);
            acc1 = MFMA16(a1[1], b1, acc1);
            acc1 = MFMA16(a1[2], b2, acc1);
            acc1 = MFMA16(a1[3], b3, acc1);
            int node = nt * 16 + l15;
            half4_t o0, o1;
#pragma unroll
            for (int r = 0; r < 4; ++r) {
                o0[r] = (half_t)fast_tanh(acc0[r] + bv0[r]);
                o1[r] = (half_t)fast_tanh(acc1[r] + bv1[r]);
            }
            *(half4_t*)&sh1[node * 264 + w * 32 + lk * 4] = o0;
            *(half4_t*)&sh1[node * 264 + w * 32 + 16 + lk * 4] = o1;
        }
    }
    __syncthreads();

    // ---- GEMM2: h2[node][128] = tanh(h1 @ W2 + b2); wave owns nout [w*16,w*16+16) ----
    half4_t h2r[4];
    {
        half8 a[8];
#pragma unroll
        for (int ks = 0; ks < 8; ++ks)
            a[ks] = *(const half8*)&Wt2[(w * 16 + l15) * 256 + ks * 32 + lk * 8];
        f32x4 bv = *(const f32x4*)&bu2[w * 16 + lk * 4];
#pragma unroll
        for (int nt = 0; nt < 4; ++nt) {
            f32x4 acc = {0.f, 0.f, 0.f, 0.f};
#pragma unroll
            for (int ks = 0; ks < 8; ++ks) {
                half8 b = *(const half8*)&sh1[(nt * 16 + l15) * 264 + ks * 32 + lk * 8];
                acc = MFMA16(a[ks], b, acc);
            }
#pragma unroll
            for (int r = 0; r < 4; ++r)
                h2r[nt][r] = (half_t)fast_tanh(acc[r] + bv[r]);
        }
    }
    __syncthreads();  // all GEMM2 reads of sh1 done before h2 overlay
#pragma unroll
    for (int nt = 0; nt < 4; ++nt)
        *(half4_t*)&sh1[(nt * 16 + l15) * 136 + w * 16 + lk * 4] = h2r[nt];
    __syncthreads();

    // ---- GEMM3 + l2norm: waves 0..3, wave w owns nodes [w*16,(w+1)*16) ----
    if (w < 4) {
        half8 a0[4], a1[4], b[4];
#pragma unroll
        for (int ks = 0; ks < 4; ++ks) {
            a0[ks] = *(const half8*)&Wt3[l15 * 128 + ks * 32 + lk * 8];
            a1[ks] = *(const half8*)&Wt3[(16 + l15) * 128 + ks * 32 + lk * 8];
            b[ks]  = *(const half8*)&sh1[(w * 16 + l15) * 136 + ks * 32 + lk * 8];
        }
        f32x4 acc0 = {0.f, 0.f, 0.f, 0.f}, acc1 = {0.f, 0.f, 0.f, 0.f};
#pragma unroll
        for (int ks = 0; ks < 4; ++ks) {
            acc0 = MFMA16(a0[ks], b[ks], acc0);
            acc1 = MFMA16(a1[ks], b[ks], acc1);
        }
        f32x4 bv0 = *(const f32x4*)&bu3[lk * 4];
        f32x4 bv1 = *(const f32x4*)&bu3[16 + lk * 4];
        float v0[4], v1[4];
        float ss = 0.f;
#pragma unroll
        for (int r = 0; r < 4; ++r) {
            v0[r] = fast_tanh(acc0[r] + bv0[r]);
            v1[r] = fast_tanh(acc1[r] + bv1[r]);
            ss += v0[r] * v0[r] + v1[r] * v1[r];
        }
        ss += __shfl_xor(ss, 16);
        ss += __shfl_xor(ss, 32);
        float sc = rsqrtf(fmaxf(ss, 1e-12f));
        int node = node0 + w * 16 + l15;
        if (node < n) {
            f32x4 o0 = {v0[0] * sc, v0[1] * sc, v0[2] * sc, v0[3] * sc};
            f32x4 o1 = {v1[0] * sc, v1[1] * sc, v1[2] * sc, v1[3] * sc};
            *(f32x4*)&reps_out[(size_t)node * 32 + lk * 4] = o0;
            *(f32x4*)&reps_out[(size_t)node * 32 + 16 + lk * 4] = o1;
        }
    }
}

// ---------------- readout: gather generators (nan->0), 32->64->32->1 ----------------
__global__ __launch_bounds__(256) void k_readout(
    const float* __restrict__ reps, const int* __restrict__ gen,
    const float* __restrict__ Wr1, const float* __restrict__ br1,
    const float* __restrict__ Wr2, const float* __restrict__ br2,
    const float* __restrict__ Wr3, const float* __restrict__ br3,
    float* __restrict__ out, int ngen) {
    __shared__ float sW1[32 * 64];
    __shared__ float sW2[64 * 32];
    __shared__ float sb1[64];
    __shared__ float sb2[32];
    __shared__ float sW3r[32];
    __shared__ float sb3;
    int tid = threadIdx.x;
    for (int i = tid; i < 2048; i += 256) sW1[i] = Wr1[i];
    for (int i = tid; i < 2048; i += 256) sW2[i] = Wr2[i];
    if (tid < 64) sb1[tid] = br1[tid];
    if (tid < 32) sb2[tid] = br2[tid];
    if (tid < 32) sW3r[tid] = Wr3[tid];
    if (tid == 0) sb3 = br3[0];
    __syncthreads();
    int ig = blockIdx.x * 256 + tid;
    if (ig >= ngen) return;
    int node = gen[ig];
    float g[32];
#pragma unroll
    for (int q = 0; q < 8; ++q) {
        float4 v = *reinterpret_cast<const float4*>(&reps[(size_t)node * 32 + q * 4]);
        g[q * 4 + 0] = (v.x != v.x) ? 0.f : v.x;
        g[q * 4 + 1] = (v.y != v.y) ? 0.f : v.y;
        g[q * 4 + 2] = (v.z != v.z) ? 0.f : v.z;
        g[q * 4 + 3] = (v.w != v.w) ? 0.f : v.w;
    }
    float a[64];
#pragma unroll
    for (int o = 0; o < 64; ++o) {
        float acc = sb1[o];
#pragma unroll
        for (int k = 0; k < 32; ++k) acc = fmaf(g[k], sW1[k * 64 + o], acc);
        a[o] = tanhf(acc);
    }
    float b[32];
#pragma unroll
    for (int o = 0; o < 32; ++o) {
        float acc = sb2[o];
#pragma unroll
        for (int k = 0; k < 64; ++k) acc = fmaf(a[k], sW2[k * 32 + o], acc);
        b[o] = tanhf(acc);
    }
    float acc = sb3;
#pragma unroll
    for (int k = 0; k < 32; ++k) acc = fmaf(b[k], sW3r[k], acc);
    out[ig] = acc;
}

extern "C" void kernel_launch(void* const* d_in, const int* in_sizes, int n_in,
                              void* d_out, int out_size, void* d_ws, size_t ws_size,
                              hipStream_t stream) {
    const float* x   = (const float*)d_in[0];
    const float* ew  = (const float*)d_in[1];
    const float* Wu1 = (const float*)d_in[2];
    const float* bu1 = (const float*)d_in[3];
    const float* Wu2 = (const float*)d_in[4];
    const float* bu2 = (const float*)d_in[5];
    const float* Wu3 = (const float*)d_in[6];
    const float* bu3 = (const float*)d_in[7];
    const float* Wr1 = (const float*)d_in[8];
    const float* br1 = (const float*)d_in[9];
    const float* Wr2 = (const float*)d_in[10];
    const float* br2 = (const float*)d_in[11];
    const float* Wr3 = (const float*)d_in[12];
    const float* br3 = (const float*)d_in[13];
    const int* edges = (const int*)d_in[14];
    const int* gen   = (const int*)d_in[15];

    const int n    = in_sizes[0] / 8;
    const int E    = in_sizes[1] / 4;
    const int ngen = in_sizes[15];
    const int* dst = edges;      // node_idx (segment ids)
    const int* src = edges + E;  // nbr_idx (gather source)
    float* out = (float*)d_out;

    const int nblk = (n + 63) / 64;
    const int npad = nblk * 64;
    const int npad8 = ((npad + 7) / 8) * 8;

    // workspace layout (256B aligned slabs)
    char* ws = (char*)d_ws;
    size_t off = 0;
    auto alloc = [&](size_t bytes) -> char* {
        char* p = ws + off;
        off = (off + bytes + 255) & ~(size_t)255;
        return p;
    };
    int* deg       = (int*)alloc((size_t)n * 4);
    int* row_start = (int*)alloc((size_t)(n + 1) * 4);
    int* cursor    = (int*)alloc((size_t)n * 4);
    int* bsum      = (int*)alloc(1024);
    int* boff      = (int*)alloc(1024);
    int2* pairs    = (int2*)alloc((size_t)E * 8);     // {src, eid} per CSR slot
    half_t* Hbuf   = (half_t*)alloc((size_t)npad * 128 * 2);
    float* repsA   = (float*)alloc((size_t)npad * 32 * 4);
    float* repsB   = (float*)alloc((size_t)npad * 32 * 4);
    half_t* Wt1    = (half_t*)alloc(32768 * 2);
    half_t* Wt2    = (half_t*)alloc(32768 * 2);
    half_t* Wt3    = (half_t*)alloc(4096 * 2);

    k_wprep<<<272, 256, 0, stream>>>(Wu1, Wu2, Wu3, Wt1, Wt2, Wt3);

    hipMemsetAsync(deg, 0, (size_t)n * 4, stream);
    k_hist<<<(E + 255) / 256, 256, 0, stream>>>(dst, deg, E);
    int nb = (n + 1023) / 1024;
    k_bsum<<<nb, 1024, 0, stream>>>(deg, bsum, n);
    k_scanb<<<1, 128, 0, stream>>>(bsum, boff, nb);
    k_scanfinal<<<nb, 1024, 0, stream>>>(deg, boff, row_start, cursor, n, E);
    k_scatter<<<(E + 255) / 256, 256, 0, stream>>>(dst, src, cursor, pairs, E);
    k_prepare<<<(n + 255) / 256, 256, 0, stream>>>(x, ew, row_start, pairs, repsA, n);

    float* cur = repsA;
    float* nxt = repsB;
    for (int it = 0; it < 3; ++it) {
        k_gather<<<npad8 / 8, 256, 0, stream>>>(cur, row_start, pairs, Hbuf, n, npad);
        k_mlp<<<nblk, 512, 0, stream>>>(Hbuf, Wt1, Wt2, Wt3, bu1, bu2, bu3, nxt, n);
        float* t = cur; cur = nxt; nxt = t;
    }

    k_readout<<<(ngen + 255) / 256, 256, 0, stream>>>(cur, gen, Wr1, br1, Wr2, br2,
                                                      Wr3, br3, out, ngen);
}

// Round 5
// 590.966 us; speedup vs baseline: 5.5232x; 1.0267x over previous
//
#include <hip/hip_runtime.h>
#include <cfloat>
#include <cmath>

// ---------------------------------------------------------------------------
// GNN message passing — fp16 MFMA, round 5.
//  R5 changes (theory-first):
//   1. reps stored fp16 [n][32] (64B rows): halves gather fetch (1 line per
//      neighbor instead of 2) and reps write traffic. H was already fp16 for
//      MFMA — quantization just moves one step earlier.
//   2. k_gather FUSED into k_mlp via LDS H-tile (64x136 fp16): kills the
//      25.6MB H buffer round-trip (~77MB/iter) and 3 dispatches. GEMM1 B-frags
//      read from LDS (272B row stride -> 2-way bank conflict = free, m136).
//      h2 overlays dead sH (gather data consumed by GEMM1).
//  Scatter left as-is: r4 showed it is random-transaction bound (write-size
//  cut did NOT help) -> needs binned partition, deferred to next round.
// MFMA mapping (verified r3/r4): D=A*B, A=W^T[nout][k], B=H[node][k]; D:
// col=lane&15=node, row=(lane>>4)*4+reg=nout.
// ---------------------------------------------------------------------------

typedef _Float16 half_t;
typedef _Float16 half8 __attribute__((ext_vector_type(8)));
typedef _Float16 half4_t __attribute__((ext_vector_type(4)));
typedef float f32x4 __attribute__((ext_vector_type(4)));

__device__ __forceinline__ float fast_tanh(float x) {
    return 1.0f - 2.0f / (1.0f + __expf(2.0f * x));
}

__device__ __forceinline__ half_t cvt_clamp(float v) {
    return (half_t)fminf(fmaxf(v, -60000.f), 60000.f);
}

// ---------------- CSR build ----------------
__global__ void k_hist(const int* __restrict__ dst, int* __restrict__ deg, int E) {
    int e = blockIdx.x * 256 + threadIdx.x;
    if (e < E) atomicAdd(&deg[dst[e]], 1);
}

__global__ void k_bsum(const int* __restrict__ deg, int* __restrict__ bsum, int n) {
    __shared__ int sh[1024];
    int t = threadIdx.x;
    int i = blockIdx.x * 1024 + t;
    sh[t] = (i < n) ? deg[i] : 0;
    __syncthreads();
    for (int s = 512; s > 0; s >>= 1) {
        if (t < s) sh[t] += sh[t + s];
        __syncthreads();
    }
    if (t == 0) bsum[blockIdx.x] = sh[0];
}

__global__ void k_scanb(const int* __restrict__ bsum, int* __restrict__ boff, int nb) {
    __shared__ int sh[128];
    int t = threadIdx.x;
    int v = (t < nb) ? bsum[t] : 0;
    sh[t] = v;
    __syncthreads();
    for (int s = 1; s < 128; s <<= 1) {
        int u = (t >= s) ? sh[t - s] : 0;
        __syncthreads();
        sh[t] += u;
        __syncthreads();
    }
    boff[t] = sh[t] - v;  // exclusive
}

__global__ void k_scanfinal(const int* __restrict__ deg, const int* __restrict__ boff,
                            int* __restrict__ row_start, int* __restrict__ cursor,
                            int n, int E) {
    __shared__ int sh[1024];
    int t = threadIdx.x;
    int i = blockIdx.x * 1024 + t;
    int v = (i < n) ? deg[i] : 0;
    sh[t] = v;
    __syncthreads();
    for (int s = 1; s < 1024; s <<= 1) {
        int u = (t >= s) ? sh[t - s] : 0;
        __syncthreads();
        sh[t] += u;
        __syncthreads();
    }
    int excl = sh[t] - v + boff[blockIdx.x];
    if (i < n) { row_start[i] = excl; cursor[i] = excl; }
    if (i == n) row_start[n] = E;
}

__global__ void k_scatter(const int* __restrict__ dst, const int* __restrict__ src,
                          int* __restrict__ cursor, int2* __restrict__ pairs, int E) {
    int e = blockIdx.x * 256 + threadIdx.x;
    if (e < E) {
        int d = dst[e];
        int p = atomicAdd(&cursor[d], 1);
        pairs[p] = make_int2(src[e], e);
    }
}

// ---------------- prepare (fp32 stats -> reps fp16 [n][32]) ----------------
__global__ void k_prepare(const float* __restrict__ x, const float* __restrict__ ew,
                          const int* __restrict__ row_start, const int2* __restrict__ pairs,
                          half_t* __restrict__ reps, int n) {
    int v = blockIdx.x * 256 + threadIdx.x;
    if (v >= n) return;
    int s0 = row_start[v], s1 = row_start[v + 1];
    float4 s = {0.f, 0.f, 0.f, 0.f};
    float4 mx = {-INFINITY, -INFINITY, -INFINITY, -INFINITY};
    float4 mn = {INFINITY, INFINITY, INFINITY, INFINITY};
    const float4* ew4 = reinterpret_cast<const float4*>(ew);
    for (int e = s0; e < s1; ++e) {
        float4 w = ew4[pairs[e].y];
        s.x += w.x; s.y += w.y; s.z += w.z; s.w += w.w;
        mx.x = fmaxf(mx.x, w.x); mx.y = fmaxf(mx.y, w.y);
        mx.z = fmaxf(mx.z, w.z); mx.w = fmaxf(mx.w, w.w);
        mn.x = fminf(mn.x, w.x); mn.y = fminf(mn.y, w.y);
        mn.z = fminf(mn.z, w.z); mn.w = fminf(mn.w, w.w);
    }
    float cnt = fmaxf((float)(s1 - s0), 1.0f);
    if (s1 == s0) {
        mx = {-FLT_MAX, -FLT_MAX, -FLT_MAX, -FLT_MAX};
        mn = {FLT_MAX, FLT_MAX, FLT_MAX, FLT_MAX};
    }
    float4 mean = {s.x / cnt, s.y / cnt, s.z / cnt, s.w / cnt};
    const float4* x4 = reinterpret_cast<const float4*>(x);
    float4 x0 = x4[v * 2 + 0], x1 = x4[v * 2 + 1];

    half_t* o = &reps[(size_t)v * 32];
    half8 c0 = {cvt_clamp(x0.x), cvt_clamp(x0.y), cvt_clamp(x0.z), cvt_clamp(x0.w),
                cvt_clamp(x1.x), cvt_clamp(x1.y), cvt_clamp(x1.z), cvt_clamp(x1.w)};
    half8 c1 = {cvt_clamp(mean.x), cvt_clamp(mean.y), cvt_clamp(mean.z), cvt_clamp(mean.w),
                cvt_clamp(mx.x), cvt_clamp(mx.y), cvt_clamp(mx.z), cvt_clamp(mx.w)};
    half8 c2 = {cvt_clamp(mn.x), cvt_clamp(mn.y), cvt_clamp(mn.z), cvt_clamp(mn.w),
                cvt_clamp(s.x), cvt_clamp(s.y), cvt_clamp(s.z), cvt_clamp(s.w)};
    half8 c3 = {(half_t)0.f, (half_t)0.f, (half_t)0.f, (half_t)0.f,
                (half_t)0.f, (half_t)0.f, (half_t)0.f, (half_t)0.f};
    *(half8*)&o[0] = c0;
    *(half8*)&o[8] = c1;
    *(half8*)&o[16] = c2;
    *(half8*)&o[24] = c3;
}

// ---------------- weight prep: fp32 [k][n] -> fp16 [n][k] ----------------
__global__ void k_wprep(const float* __restrict__ Wu1, const float* __restrict__ Wu2,
                        const float* __restrict__ Wu3, half_t* __restrict__ Wt1,
                        half_t* __restrict__ Wt2, half_t* __restrict__ Wt3) {
    int i = blockIdx.x * 256 + threadIdx.x;
    if (i < 32768) {
        int nrow = i >> 7, k = i & 127;
        Wt1[i] = (half_t)Wu1[k * 256 + nrow];
    } else if (i < 65536) {
        int j = i - 32768;
        int nrow = j >> 8, k = j & 255;
        Wt2[j] = (half_t)Wu2[k * 128 + nrow];
    } else if (i < 69632) {
        int j = i - 65536;
        int nrow = j >> 7, k = j & 127;
        Wt3[j] = (half_t)Wu3[k * 32 + nrow];
    }
}

// ---------------- fused iter: gather(LDS) + 3-layer MFMA MLP + l2norm ----------------
// 512 threads (8 waves), 64 nodes/block.
// LDS: sH[64][136] fp16 (gather output H, later h2 overlay) + sh1[64][264] fp16.
#define MFMA16(a, b, c) __builtin_amdgcn_mfma_f32_16x16x32_f16((a), (b), (c), 0, 0, 0)

__global__ __launch_bounds__(512, 4) void k_mlp(
    const half_t* __restrict__ reps_in,
    const int* __restrict__ row_start, const int2* __restrict__ pairs,
    const half_t* __restrict__ Wt1, const half_t* __restrict__ Wt2,
    const half_t* __restrict__ Wt3,
    const float* __restrict__ bu1, const float* __restrict__ bu2,
    const float* __restrict__ bu3,
    half_t* __restrict__ reps_out, int n) {
    __shared__ half_t sH[64 * 136];    // H[64][128] (+8 pad); later h2[64][128]
    __shared__ half_t sh1[64 * 264];   // h1[64][256] (+8 pad)

    const int tid = threadIdx.x;
    const int w   = tid >> 6;          // wave 0..7
    const int l15 = tid & 15;
    const int lk  = (tid & 63) >> 4;   // k-group 0..3
    const int node0 = blockIdx.x * 64;

    // ---- gather phase: 16 groups of 32 lanes, 4 nodes each; lane = feature ----
    {
        int g = tid >> 5, lane = tid & 31;
        for (int i = 0; i < 4; ++i) {
            int nl = g * 4 + i;
            int node = node0 + nl;
            float r = 0.f, s = 0.f, mx = -INFINITY, mn = INFINITY;
            int d0 = 0, d1 = 0;
            if (node < n) {
                r = (float)reps_in[(size_t)node * 32 + lane];
                d0 = row_start[node];
                d1 = row_start[node + 1];
                for (int e0 = d0; e0 < d1; e0 += 32) {
                    int m = d1 - e0; if (m > 32) m = 32;
                    int idx = (e0 + lane < d1) ? pairs[e0 + lane].x : 0;
                    int j = 0;
                    for (; j + 4 <= m; j += 4) {
                        int n0 = __shfl(idx, j, 32);
                        int n1 = __shfl(idx, j + 1, 32);
                        int n2 = __shfl(idx, j + 2, 32);
                        int n3 = __shfl(idx, j + 3, 32);
                        float v0 = (float)reps_in[(size_t)n0 * 32 + lane];
                        float v1 = (float)reps_in[(size_t)n1 * 32 + lane];
                        float v2 = (float)reps_in[(size_t)n2 * 32 + lane];
                        float v3 = (float)reps_in[(size_t)n3 * 32 + lane];
                        s += (v0 + v1) + (v2 + v3);
                        mx = fmaxf(mx, fmaxf(fmaxf(v0, v1), fmaxf(v2, v3)));
                        mn = fminf(mn, fminf(fminf(v0, v1), fminf(v2, v3)));
                    }
                    for (; j < m; ++j) {
                        int nb = __shfl(idx, j, 32);
                        float v = (float)reps_in[(size_t)nb * 32 + lane];
                        s += v;
                        mx = fmaxf(mx, v);
                        mn = fminf(mn, v);
                    }
                }
            }
            float cnt = fmaxf((float)(d1 - d0), 1.f);
            if (d1 == d0) { mx = -FLT_MAX; mn = FLT_MAX; }
            float mean = s / cnt;
            // pad nodes (node>=n) write junk-free constants; their D columns
            // are never stored (node<n guard at the end).
            sH[nl * 136 + lane]      = cvt_clamp(r);
            sH[nl * 136 + 32 + lane] = cvt_clamp(mean);
            sH[nl * 136 + 64 + lane] = cvt_clamp(mx);
            sH[nl * 136 + 96 + lane] = cvt_clamp(mn);
        }
    }
    __syncthreads();

    // ---- GEMM1: h1 = tanh(H @ W1 + b1); wave owns nout [w*32, w*32+32) ----
    {
        half8 a0[4], a1[4];
#pragma unroll
        for (int ks = 0; ks < 4; ++ks) {
            a0[ks] = *(const half8*)&Wt1[(w * 32 + l15) * 128 + ks * 32 + lk * 8];
            a1[ks] = *(const half8*)&Wt1[(w * 32 + 16 + l15) * 128 + ks * 32 + lk * 8];
        }
        f32x4 bv0 = *(const f32x4*)&bu1[w * 32 + lk * 4];
        f32x4 bv1 = *(const f32x4*)&bu1[w * 32 + 16 + lk * 4];
#pragma unroll
        for (int nt = 0; nt < 4; ++nt) {
            const half_t* hrow = &sH[(nt * 16 + l15) * 136 + lk * 8];
            half8 b0 = *(const half8*)&hrow[0];
            half8 b1 = *(const half8*)&hrow[32];
            half8 b2 = *(const half8*)&hrow[64];
            half8 b3 = *(const half8*)&hrow[96];
            f32x4 acc0 = {0.f, 0.f, 0.f, 0.f}, acc1 = {0.f, 0.f, 0.f, 0.f};
            acc0 = MFMA16(a0[0], b0, acc0);
            acc0 = MFMA16(a0[1], b1, acc0);
            acc0 = MFMA16(a0[2], b2, acc0);
            acc0 = MFMA16(a0[3], b3, acc0);
            acc1 = MFMA16(a1[0], b0, acc1);
            acc1 = MFMA16(a1[1], b1, acc1);
            acc1 = MFMA16(a1[2], b2, acc1);
            acc1 = MFMA16(a1[3], b3, acc1);
            int node = nt * 16 + l15;
            half4_t o0, o1;
#pragma unroll
            for (int r = 0; r < 4; ++r) {
                o0[r] = (half_t)fast_tanh(acc0[r] + bv0[r]);
                o1[r] = (half_t)fast_tanh(acc1[r] + bv1[r]);
            }
            *(half4_t*)&sh1[node * 264 + w * 32 + lk * 4] = o0;
            *(half4_t*)&sh1[node * 264 + w * 32 + 16 + lk * 4] = o1;
        }
    }
    __syncthreads();   // all GEMM1 sH reads + sh1 writes complete

    // ---- GEMM2: h2 = tanh(h1 @ W2 + b2) -> overlay into sH (dead) ----
    {
        half8 a[8];
#pragma unroll
        for (int ks = 0; ks < 8; ++ks)
            a[ks] = *(const half8*)&Wt2[(w * 16 + l15) * 256 + ks * 32 + lk * 8];
        f32x4 bv = *(const f32x4*)&bu2[w * 16 + lk * 4];
#pragma unroll
        for (int nt = 0; nt < 4; ++nt) {
            f32x4 acc = {0.f, 0.f, 0.f, 0.f};
#pragma unroll
            for (int ks = 0; ks < 8; ++ks) {
                half8 b = *(const half8*)&sh1[(nt * 16 + l15) * 264 + ks * 32 + lk * 8];
                acc = MFMA16(a[ks], b, acc);
            }
            half4_t o;
#pragma unroll
            for (int r = 0; r < 4; ++r)
                o[r] = (half_t)fast_tanh(acc[r] + bv[r]);
            *(half4_t*)&sH[(nt * 16 + l15) * 136 + w * 16 + lk * 4] = o;
        }
    }
    __syncthreads();   // h2 fully written

    // ---- GEMM3 + l2norm: waves 0..3, wave w owns nodes [w*16,(w+1)*16) ----
    if (w < 4) {
        half8 a0[4], a1[4], b[4];
#pragma unroll
        for (int ks = 0; ks < 4; ++ks) {
            a0[ks] = *(const half8*)&Wt3[l15 * 128 + ks * 32 + lk * 8];
            a1[ks] = *(const half8*)&Wt3[(16 + l15) * 128 + ks * 32 + lk * 8];
            b[ks]  = *(const half8*)&sH[(w * 16 + l15) * 136 + ks * 32 + lk * 8];
        }
        f32x4 acc0 = {0.f, 0.f, 0.f, 0.f}, acc1 = {0.f, 0.f, 0.f, 0.f};
#pragma unroll
        for (int ks = 0; ks < 4; ++ks) {
            acc0 = MFMA16(a0[ks], b[ks], acc0);
            acc1 = MFMA16(a1[ks], b[ks], acc1);
        }
        f32x4 bv0 = *(const f32x4*)&bu3[lk * 4];
        f32x4 bv1 = *(const f32x4*)&bu3[16 + lk * 4];
        float v0[4], v1[4];
        float ss = 0.f;
#pragma unroll
        for (int r = 0; r < 4; ++r) {
            v0[r] = fast_tanh(acc0[r] + bv0[r]);
            v1[r] = fast_tanh(acc1[r] + bv1[r]);
            ss += v0[r] * v0[r] + v1[r] * v1[r];
        }
        ss += __shfl_xor(ss, 16);
        ss += __shfl_xor(ss, 32);
        float sc = rsqrtf(fmaxf(ss, 1e-12f));
        int node = node0 + w * 16 + l15;
        if (node < n) {
            half4_t o0, o1;
#pragma unroll
            for (int r = 0; r < 4; ++r) {
                o0[r] = (half_t)(v0[r] * sc);
                o1[r] = (half_t)(v1[r] * sc);
            }
            *(half4_t*)&reps_out[(size_t)node * 32 + lk * 4] = o0;
            *(half4_t*)&reps_out[(size_t)node * 32 + 16 + lk * 4] = o1;
        }
    }
}

// ---------------- readout: gather generators (nan->0), 32->64->32->1 ----------------
__global__ __launch_bounds__(256) void k_readout(
    const half_t* __restrict__ reps, const int* __restrict__ gen,
    const float* __restrict__ Wr1, const float* __restrict__ br1,
    const float* __restrict__ Wr2, const float* __restrict__ br2,
    const float* __restrict__ Wr3, const float* __restrict__ br3,
    float* __restrict__ out, int ngen) {
    __shared__ float sW1[32 * 64];
    __shared__ float sW2[64 * 32];
    __shared__ float sb1[64];
    __shared__ float sb2[32];
    __shared__ float sW3r[32];
    __shared__ float sb3;
    int tid = threadIdx.x;
    for (int i = tid; i < 2048; i += 256) sW1[i] = Wr1[i];
    for (int i = tid; i < 2048; i += 256) sW2[i] = Wr2[i];
    if (tid < 64) sb1[tid] = br1[tid];
    if (tid < 32) sb2[tid] = br2[tid];
    if (tid < 32) sW3r[tid] = Wr3[tid];
    if (tid == 0) sb3 = br3[0];
    __syncthreads();
    int ig = blockIdx.x * 256 + tid;
    if (ig >= ngen) return;
    int node = gen[ig];
    float g[32];
#pragma unroll
    for (int q = 0; q < 4; ++q) {
        half8 v = *(const half8*)&reps[(size_t)node * 32 + q * 8];
#pragma unroll
        for (int r = 0; r < 8; ++r) {
            float f = (float)v[r];
            g[q * 8 + r] = (f != f) ? 0.f : f;
        }
    }
    float a[64];
#pragma unroll
    for (int o = 0; o < 64; ++o) {
        float acc = sb1[o];
#pragma unroll
        for (int k = 0; k < 32; ++k) acc = fmaf(g[k], sW1[k * 64 + o], acc);
        a[o] = tanhf(acc);
    }
    float b[32];
#pragma unroll
    for (int o = 0; o < 32; ++o) {
        float acc = sb2[o];
#pragma unroll
        for (int k = 0; k < 64; ++k) acc = fmaf(a[k], sW2[k * 32 + o], acc);
        b[o] = tanhf(acc);
    }
    float acc = sb3;
#pragma unroll
    for (int k = 0; k < 32; ++k) acc = fmaf(b[k], sW3r[k], acc);
    out[ig] = acc;
}

extern "C" void kernel_launch(void* const* d_in, const int* in_sizes, int n_in,
                              void* d_out, int out_size, void* d_ws, size_t ws_size,
                              hipStream_t stream) {
    const float* x   = (const float*)d_in[0];
    const float* ew  = (const float*)d_in[1];
    const float* Wu1 = (const float*)d_in[2];
    const float* bu1 = (const float*)d_in[3];
    const float* Wu2 = (const float*)d_in[4];
    const float* bu2 = (const float*)d_in[5];
    const float* Wu3 = (const float*)d_in[6];
    const float* bu3 = (const float*)d_in[7];
    const float* Wr1 = (const float*)d_in[8];
    const float* br1 = (const float*)d_in[9];
    const float* Wr2 = (const float*)d_in[10];
    const float* br2 = (const float*)d_in[11];
    const float* Wr3 = (const float*)d_in[12];
    const float* br3 = (const float*)d_in[13];
    const int* edges = (const int*)d_in[14];
    const int* gen   = (const int*)d_in[15];

    const int n    = in_sizes[0] / 8;
    const int E    = in_sizes[1] / 4;
    const int ngen = in_sizes[15];
    const int* dst = edges;      // node_idx (segment ids)
    const int* src = edges + E;  // nbr_idx (gather source)
    float* out = (float*)d_out;

    const int nblk = (n + 63) / 64;
    const int npad = nblk * 64;

    // workspace layout (256B aligned slabs)
    char* ws = (char*)d_ws;
    size_t off = 0;
    auto alloc = [&](size_t bytes) -> char* {
        char* p = ws + off;
        off = (off + bytes + 255) & ~(size_t)255;
        return p;
    };
    int* deg       = (int*)alloc((size_t)n * 4);
    int* row_start = (int*)alloc((size_t)(n + 1) * 4);
    int* cursor    = (int*)alloc((size_t)n * 4);
    int* bsum      = (int*)alloc(1024);
    int* boff      = (int*)alloc(1024);
    int2* pairs    = (int2*)alloc((size_t)E * 8);      // {src, eid} per CSR slot
    half_t* repsA  = (half_t*)alloc((size_t)npad * 32 * 2);
    half_t* repsB  = (half_t*)alloc((size_t)npad * 32 * 2);
    half_t* Wt1    = (half_t*)alloc(32768 * 2);
    half_t* Wt2    = (half_t*)alloc(32768 * 2);
    half_t* Wt3    = (half_t*)alloc(4096 * 2);

    k_wprep<<<272, 256, 0, stream>>>(Wu1, Wu2, Wu3, Wt1, Wt2, Wt3);

    hipMemsetAsync(deg, 0, (size_t)n * 4, stream);
    k_hist<<<(E + 255) / 256, 256, 0, stream>>>(dst, deg, E);
    int nb = (n + 1023) / 1024;
    k_bsum<<<nb, 1024, 0, stream>>>(deg, bsum, n);
    k_scanb<<<1, 128, 0, stream>>>(bsum, boff, nb);
    k_scanfinal<<<nb, 1024, 0, stream>>>(deg, boff, row_start, cursor, n, E);
    k_scatter<<<(E + 255) / 256, 256, 0, stream>>>(dst, src, cursor, pairs, E);
    k_prepare<<<(n + 255) / 256, 256, 0, stream>>>(x, ew, row_start, pairs, repsA, n);

    half_t* cur = repsA;
    half_t* nxt = repsB;
    for (int it = 0; it < 3; ++it) {
        k_mlp<<<nblk, 512, 0, stream>>>(cur, row_start, pairs, Wt1, Wt2, Wt3,
                                        bu1, bu2, bu3, nxt, n);
        half_t* t = cur; cur = nxt; nxt = t;
    }

    k_readout<<<(ngen + 255) / 256, 256, 0, stream>>>(cur, gen, Wr1, br1, Wr2, br2,
                                                      Wr3, br3, out, ngen);
}

// Round 6
// 409.233 us; speedup vs baseline: 7.9760x; 1.4441x over previous
//
#include <hip/hip_runtime.h>
#include <cfloat>
#include <cmath>

// ---------------------------------------------------------------------------
// GNN message passing — fp16 MFMA, round 6.
//  R6 changes (theory-first):
//   1. CSR build replaced by two-phase BINNED partition:
//      k_binA: LDS bin-histogram (196 bins of 512 nodes), 1 global atomic per
//              bin per block for chunk reservation, bin-grouped coalesced
//              staging writes. Kills the 1.6M random cross-XCD atomics+stores
//              of k_hist/k_scatter and the global scan kernels.
//      k_binB: per-bin block: LDS degree count + LDS scan -> row_start, then
//              LDS-cursor scatter into a 65KB L2-resident pairs window (full
//              lines, no RMW, no cross-XCD traffic).
//   2. fast_tanh uses v_exp/v_rcp intrinsics (drops the correctly-rounded
//      fp32 divide, ~15cy/activation).
//  k_mlp structure unchanged from r5 (fused gather + 3x MFMA GEMM + l2norm).
// MFMA mapping (verified r3-r5): D=A*B, A=W^T[nout][k], B=H[node][k]; D:
// col=lane&15=node, row=(lane>>4)*4+reg=nout.
// ---------------------------------------------------------------------------

typedef _Float16 half_t;
typedef _Float16 half8 __attribute__((ext_vector_type(8)));
typedef _Float16 half4_t __attribute__((ext_vector_type(4)));
typedef float f32x4 __attribute__((ext_vector_type(4)));

#define NPB 512        // nodes per bin (power of 2: bin = dst>>9)
#define BIN_CAP 10240  // slots per bin; mean fill ~8163, +23 sigma headroom

__device__ __forceinline__ float fast_tanh(float x) {
    // 1 - 2/(1+exp(2x)) via hw exp2 + rcp (1ulp): exact +-1 saturation.
    float e = __builtin_amdgcn_exp2f(x * 2.8853900817779268f);
    return 1.0f - 2.0f * __builtin_amdgcn_rcpf(1.0f + e);
}

__device__ __forceinline__ half_t cvt_clamp(float v) {
    return (half_t)fminf(fmaxf(v, -60000.f), 60000.f);
}

// ---------------- phase A: bin edges (coalesced staging) ----------------
__global__ __launch_bounds__(256) void k_binA(
    const int* __restrict__ dst, const int* __restrict__ src,
    int* __restrict__ binCnt, int2* __restrict__ staged, int E, int nbins) {
    __shared__ int cnt[256], base[256], cur[256];
    int t = threadIdx.x;
    cnt[t] = 0;
    cur[t] = 0;
    __syncthreads();
    int e0 = blockIdx.x * 8192;
#pragma unroll 4
    for (int i = 0; i < 32; ++i) {
        int e = e0 + i * 256 + t;
        if (e < E) atomicAdd(&cnt[dst[e] >> 9], 1);
    }
    __syncthreads();
    if (t < nbins && cnt[t] > 0) base[t] = atomicAdd(&binCnt[t], cnt[t]);
    __syncthreads();
#pragma unroll 4
    for (int i = 0; i < 32; ++i) {
        int e = e0 + i * 256 + t;
        if (e < E) {
            int d = dst[e];
            int b = d >> 9;
            int j = base[b] + atomicAdd(&cur[b], 1);
            if (j < BIN_CAP)  // statistically unreachable; guards OOB
                staged[(size_t)b * BIN_CAP + j] =
                    make_int2(src[e], ((d & (NPB - 1)) << 21) | e);
        }
    }
}

// ---------------- bin-count exclusive scan (nbins <= 256) ----------------
__global__ void k_scanN(const int* __restrict__ binCnt, int* __restrict__ binStart,
                        int* __restrict__ row_start, int nbins, int n, int E) {
    __shared__ int sh[256];
    int t = threadIdx.x;
    int v = (t < nbins) ? binCnt[t] : 0;
    sh[t] = v;
    __syncthreads();
    for (int s = 1; s < 256; s <<= 1) {
        int u = (t >= s) ? sh[t - s] : 0;
        __syncthreads();
        sh[t] += u;
        __syncthreads();
    }
    if (t < nbins) binStart[t] = sh[t] - v;
    if (t == 0) row_start[n] = E;
}

// ---------------- phase B: per-bin local CSR (LDS atomics/scan) ----------------
__global__ __launch_bounds__(512) void k_binB(
    const int* __restrict__ binCnt, const int* __restrict__ binStart,
    const int2* __restrict__ staged, int* __restrict__ row_start,
    int* __restrict__ snbr, int* __restrict__ seid, int n) {
    __shared__ int deg[NPB], cur[NPB], rsl[NPB];
    int t = threadIdx.x;
    int bin = blockIdx.x;
    int cntE = min(binCnt[bin], BIN_CAP);
    int pbase = binStart[bin];
    const int2* st = staged + (size_t)bin * BIN_CAP;
    deg[t] = 0;
    cur[t] = 0;
    __syncthreads();
    for (int i = t; i < cntE; i += 512)
        atomicAdd(&deg[(st[i].y >> 21) & (NPB - 1)], 1);
    __syncthreads();
    int own = deg[t];
    for (int s = 1; s < NPB; s <<= 1) {  // inclusive Hillis-Steele
        int u = (t >= s) ? deg[t - s] : 0;
        __syncthreads();
        deg[t] += u;
        __syncthreads();
    }
    int excl = deg[t] - own;
    rsl[t] = pbase + excl;
    int node = bin * NPB + t;
    if (node < n) row_start[node] = pbase + excl;
    __syncthreads();
    for (int i = t; i < cntE; i += 512) {
        int2 v = st[i];
        int dl = (v.y >> 21) & (NPB - 1);
        int p = rsl[dl] + atomicAdd(&cur[dl], 1);
        snbr[p] = v.x;
        seid[p] = v.y & 0x1FFFFF;
    }
}

// ---------------- prepare (fp32 stats -> reps fp16 [n][32]) ----------------
__global__ void k_prepare(const float* __restrict__ x, const float* __restrict__ ew,
                          const int* __restrict__ row_start, const int* __restrict__ seid,
                          half_t* __restrict__ reps, int n) {
    int v = blockIdx.x * 256 + threadIdx.x;
    if (v >= n) return;
    int s0 = row_start[v], s1 = row_start[v + 1];
    float4 s = {0.f, 0.f, 0.f, 0.f};
    float4 mx = {-INFINITY, -INFINITY, -INFINITY, -INFINITY};
    float4 mn = {INFINITY, INFINITY, INFINITY, INFINITY};
    const float4* ew4 = reinterpret_cast<const float4*>(ew);
    for (int e = s0; e < s1; ++e) {
        float4 w = ew4[seid[e]];
        s.x += w.x; s.y += w.y; s.z += w.z; s.w += w.w;
        mx.x = fmaxf(mx.x, w.x); mx.y = fmaxf(mx.y, w.y);
        mx.z = fmaxf(mx.z, w.z); mx.w = fmaxf(mx.w, w.w);
        mn.x = fminf(mn.x, w.x); mn.y = fminf(mn.y, w.y);
        mn.z = fminf(mn.z, w.z); mn.w = fminf(mn.w, w.w);
    }
    float cnt = fmaxf((float)(s1 - s0), 1.0f);
    if (s1 == s0) {
        mx = {-FLT_MAX, -FLT_MAX, -FLT_MAX, -FLT_MAX};
        mn = {FLT_MAX, FLT_MAX, FLT_MAX, FLT_MAX};
    }
    float4 mean = {s.x / cnt, s.y / cnt, s.z / cnt, s.w / cnt};
    const float4* x4 = reinterpret_cast<const float4*>(x);
    float4 x0 = x4[v * 2 + 0], x1 = x4[v * 2 + 1];

    half_t* o = &reps[(size_t)v * 32];
    half8 c0 = {cvt_clamp(x0.x), cvt_clamp(x0.y), cvt_clamp(x0.z), cvt_clamp(x0.w),
                cvt_clamp(x1.x), cvt_clamp(x1.y), cvt_clamp(x1.z), cvt_clamp(x1.w)};
    half8 c1 = {cvt_clamp(mean.x), cvt_clamp(mean.y), cvt_clamp(mean.z), cvt_clamp(mean.w),
                cvt_clamp(mx.x), cvt_clamp(mx.y), cvt_clamp(mx.z), cvt_clamp(mx.w)};
    half8 c2 = {cvt_clamp(mn.x), cvt_clamp(mn.y), cvt_clamp(mn.z), cvt_clamp(mn.w),
                cvt_clamp(s.x), cvt_clamp(s.y), cvt_clamp(s.z), cvt_clamp(s.w)};
    half8 c3 = {(half_t)0.f, (half_t)0.f, (half_t)0.f, (half_t)0.f,
                (half_t)0.f, (half_t)0.f, (half_t)0.f, (half_t)0.f};
    *(half8*)&o[0] = c0;
    *(half8*)&o[8] = c1;
    *(half8*)&o[16] = c2;
    *(half8*)&o[24] = c3;
}

// ---------------- weight prep: fp32 [k][n] -> fp16 [n][k] ----------------
__global__ void k_wprep(const float* __restrict__ Wu1, const float* __restrict__ Wu2,
                        const float* __restrict__ Wu3, half_t* __restrict__ Wt1,
                        half_t* __restrict__ Wt2, half_t* __restrict__ Wt3) {
    int i = blockIdx.x * 256 + threadIdx.x;
    if (i < 32768) {
        int nrow = i >> 7, k = i & 127;
        Wt1[i] = (half_t)Wu1[k * 256 + nrow];
    } else if (i < 65536) {
        int j = i - 32768;
        int nrow = j >> 8, k = j & 255;
        Wt2[j] = (half_t)Wu2[k * 128 + nrow];
    } else if (i < 69632) {
        int j = i - 65536;
        int nrow = j >> 7, k = j & 127;
        Wt3[j] = (half_t)Wu3[k * 32 + nrow];
    }
}

// ---------------- fused iter: gather(LDS) + 3-layer MFMA MLP + l2norm ----------------
#define MFMA16(a, b, c) __builtin_amdgcn_mfma_f32_16x16x32_f16((a), (b), (c), 0, 0, 0)

__global__ __launch_bounds__(512, 4) void k_mlp(
    const half_t* __restrict__ reps_in,
    const int* __restrict__ row_start, const int* __restrict__ snbr,
    const half_t* __restrict__ Wt1, const half_t* __restrict__ Wt2,
    const half_t* __restrict__ Wt3,
    const float* __restrict__ bu1, const float* __restrict__ bu2,
    const float* __restrict__ bu3,
    half_t* __restrict__ reps_out, int n) {
    __shared__ half_t sH[64 * 136];    // H[64][128] (+8 pad); later h2[64][128]
    __shared__ half_t sh1[64 * 264];   // h1[64][256] (+8 pad)

    const int tid = threadIdx.x;
    const int w   = tid >> 6;          // wave 0..7
    const int l15 = tid & 15;
    const int lk  = (tid & 63) >> 4;   // k-group 0..3
    const int node0 = blockIdx.x * 64;

    // ---- gather phase: 16 groups of 32 lanes, 4 nodes each; lane = feature ----
    {
        int g = tid >> 5, lane = tid & 31;
        for (int i = 0; i < 4; ++i) {
            int nl = g * 4 + i;
            int node = node0 + nl;
            float r = 0.f, s = 0.f, mx = -INFINITY, mn = INFINITY;
            int d0 = 0, d1 = 0;
            if (node < n) {
                r = (float)reps_in[(size_t)node * 32 + lane];
                d0 = row_start[node];
                d1 = row_start[node + 1];
                for (int e0 = d0; e0 < d1; e0 += 32) {
                    int m = d1 - e0; if (m > 32) m = 32;
                    int idx = (e0 + lane < d1) ? snbr[e0 + lane] : 0;
                    int j = 0;
                    for (; j + 4 <= m; j += 4) {
                        int n0 = __shfl(idx, j, 32);
                        int n1 = __shfl(idx, j + 1, 32);
                        int n2 = __shfl(idx, j + 2, 32);
                        int n3 = __shfl(idx, j + 3, 32);
                        float v0 = (float)reps_in[(size_t)n0 * 32 + lane];
                        float v1 = (float)reps_in[(size_t)n1 * 32 + lane];
                        float v2 = (float)reps_in[(size_t)n2 * 32 + lane];
                        float v3 = (float)reps_in[(size_t)n3 * 32 + lane];
                        s += (v0 + v1) + (v2 + v3);
                        mx = fmaxf(mx, fmaxf(fmaxf(v0, v1), fmaxf(v2, v3)));
                        mn = fminf(mn, fminf(fminf(v0, v1), fminf(v2, v3)));
                    }
                    for (; j < m; ++j) {
                        int nb = __shfl(idx, j, 32);
                        float v = (float)reps_in[(size_t)nb * 32 + lane];
                        s += v;
                        mx = fmaxf(mx, v);
                        mn = fminf(mn, v);
                    }
                }
            }
            float cnt = fmaxf((float)(d1 - d0), 1.f);
            if (d1 == d0) { mx = -FLT_MAX; mn = FLT_MAX; }
            float mean = s / cnt;
            sH[nl * 136 + lane]      = cvt_clamp(r);
            sH[nl * 136 + 32 + lane] = cvt_clamp(mean);
            sH[nl * 136 + 64 + lane] = cvt_clamp(mx);
            sH[nl * 136 + 96 + lane] = cvt_clamp(mn);
        }
    }
    __syncthreads();

    // ---- GEMM1: h1 = tanh(H @ W1 + b1); wave owns nout [w*32, w*32+32) ----
    {
        half8 a0[4], a1[4];
#pragma unroll
        for (int ks = 0; ks < 4; ++ks) {
            a0[ks] = *(const half8*)&Wt1[(w * 32 + l15) * 128 + ks * 32 + lk * 8];
            a1[ks] = *(const half8*)&Wt1[(w * 32 + 16 + l15) * 128 + ks * 32 + lk * 8];
        }
        f32x4 bv0 = *(const f32x4*)&bu1[w * 32 + lk * 4];
        f32x4 bv1 = *(const f32x4*)&bu1[w * 32 + 16 + lk * 4];
#pragma unroll
        for (int nt = 0; nt < 4; ++nt) {
            const half_t* hrow = &sH[(nt * 16 + l15) * 136 + lk * 8];
            half8 b0 = *(const half8*)&hrow[0];
            half8 b1 = *(const half8*)&hrow[32];
            half8 b2 = *(const half8*)&hrow[64];
            half8 b3 = *(const half8*)&hrow[96];
            f32x4 acc0 = {0.f, 0.f, 0.f, 0.f}, acc1 = {0.f, 0.f, 0.f, 0.f};
            acc0 = MFMA16(a0[0], b0, acc0);
            acc0 = MFMA16(a0[1], b1, acc0);
            acc0 = MFMA16(a0[2], b2, acc0);
            acc0 = MFMA16(a0[3], b3, acc0);
            acc1 = MFMA16(a1[0], b0, acc1);
            acc1 = MFMA16(a1[1], b1, acc1);
            acc1 = MFMA16(a1[2], b2, acc1);
            acc1 = MFMA16(a1[3], b3, acc1);
            int node = nt * 16 + l15;
            half4_t o0, o1;
#pragma unroll
            for (int r = 0; r < 4; ++r) {
                o0[r] = (half_t)fast_tanh(acc0[r] + bv0[r]);
                o1[r] = (half_t)fast_tanh(acc1[r] + bv1[r]);
            }
            *(half4_t*)&sh1[node * 264 + w * 32 + lk * 4] = o0;
            *(half4_t*)&sh1[node * 264 + w * 32 + 16 + lk * 4] = o1;
        }
    }
    __syncthreads();

    // ---- GEMM2: h2 = tanh(h1 @ W2 + b2) -> overlay into sH (dead) ----
    {
        half8 a[8];
#pragma unroll
        for (int ks = 0; ks < 8; ++ks)
            a[ks] = *(const half8*)&Wt2[(w * 16 + l15) * 256 + ks * 32 + lk * 8];
        f32x4 bv = *(const f32x4*)&bu2[w * 16 + lk * 4];
#pragma unroll
        for (int nt = 0; nt < 4; ++nt) {
            f32x4 acc = {0.f, 0.f, 0.f, 0.f};
#pragma unroll
            for (int ks = 0; ks < 8; ++ks) {
                half8 b = *(const half8*)&sh1[(nt * 16 + l15) * 264 + ks * 32 + lk * 8];
                acc = MFMA16(a[ks], b, acc);
            }
            half4_t o;
#pragma unroll
            for (int r = 0; r < 4; ++r)
                o[r] = (half_t)fast_tanh(acc[r] + bv[r]);
            *(half4_t*)&sH[(nt * 16 + l15) * 136 + w * 16 + lk * 4] = o;
        }
    }
    __syncthreads();

    // ---- GEMM3 + l2norm: waves 0..3, wave w owns nodes [w*16,(w+1)*16) ----
    if (w < 4) {
        half8 a0[4], a1[4], b[4];
#pragma unroll
        for (int ks = 0; ks < 4; ++ks) {
            a0[ks] = *(const half8*)&Wt3[l15 * 128 + ks * 32 + lk * 8];
            a1[ks] = *(const half8*)&Wt3[(16 + l15) * 128 + ks * 32 + lk * 8];
            b[ks]  = *(const half8*)&sH[(w * 16 + l15) * 136 + ks * 32 + lk * 8];
        }
        f32x4 acc0 = {0.f, 0.f, 0.f, 0.f}, acc1 = {0.f, 0.f, 0.f, 0.f};
#pragma unroll
        for (int ks = 0; ks < 4; ++ks) {
            acc0 = MFMA16(a0[ks], b[ks], acc0);
            acc1 = MFMA16(a1[ks], b[ks], acc1);
        }
        f32x4 bv0 = *(const f32x4*)&bu3[lk * 4];
        f32x4 bv1 = *(const f32x4*)&bu3[16 + lk * 4];
        float v0[4], v1[4];
        float ss = 0.f;
#pragma unroll
        for (int r = 0; r < 4; ++r) {
            v0[r] = fast_tanh(acc0[r] + bv0[r]);
            v1[r] = fast_tanh(acc1[r] + bv1[r]);
            ss += v0[r] * v0[r] + v1[r] * v1[r];
        }
        ss += __shfl_xor(ss, 16);
        ss += __shfl_xor(ss, 32);
        float sc = rsqrtf(fmaxf(ss, 1e-12f));
        int node = node0 + w * 16 + l15;
        if (node < n) {
            half4_t o0, o1;
#pragma unroll
            for (int r = 0; r < 4; ++r) {
                o0[r] = (half_t)(v0[r] * sc);
                o1[r] = (half_t)(v1[r] * sc);
            }
            *(half4_t*)&reps_out[(size_t)node * 32 + lk * 4] = o0;
            *(half4_t*)&reps_out[(size_t)node * 32 + 16 + lk * 4] = o1;
        }
    }
}

// ---------------- readout: gather generators (nan->0), 32->64->32->1 ----------------
__global__ __launch_bounds__(256) void k_readout(
    const half_t* __restrict__ reps, const int* __restrict__ gen,
    const float* __restrict__ Wr1, const float* __restrict__ br1,
    const float* __restrict__ Wr2, const float* __restrict__ br2,
    const float* __restrict__ Wr3, const float* __restrict__ br3,
    float* __restrict__ out, int ngen) {
    __shared__ float sW1[32 * 64];
    __shared__ float sW2[64 * 32];
    __shared__ float sb1[64];
    __shared__ float sb2[32];
    __shared__ float sW3r[32];
    __shared__ float sb3;
    int tid = threadIdx.x;
    for (int i = tid; i < 2048; i += 256) sW1[i] = Wr1[i];
    for (int i = tid; i < 2048; i += 256) sW2[i] = Wr2[i];
    if (tid < 64) sb1[tid] = br1[tid];
    if (tid < 32) sb2[tid] = br2[tid];
    if (tid < 32) sW3r[tid] = Wr3[tid];
    if (tid == 0) sb3 = br3[0];
    __syncthreads();
    int ig = blockIdx.x * 256 + tid;
    if (ig >= ngen) return;
    int node = gen[ig];
    float g[32];
#pragma unroll
    for (int q = 0; q < 4; ++q) {
        half8 v = *(const half8*)&reps[(size_t)node * 32 + q * 8];
#pragma unroll
        for (int r = 0; r < 8; ++r) {
            float f = (float)v[r];
            g[q * 8 + r] = (f != f) ? 0.f : f;
        }
    }
    float a[64];
#pragma unroll
    for (int o = 0; o < 64; ++o) {
        float acc = sb1[o];
#pragma unroll
        for (int k = 0; k < 32; ++k) acc = fmaf(g[k], sW1[k * 64 + o], acc);
        a[o] = fast_tanh(acc);
    }
    float b[32];
#pragma unroll
    for (int o = 0; o < 32; ++o) {
        float acc = sb2[o];
#pragma unroll
        for (int k = 0; k < 64; ++k) acc = fmaf(a[k], sW2[k * 32 + o], acc);
        b[o] = fast_tanh(acc);
    }
    float acc = sb3;
#pragma unroll
    for (int k = 0; k < 32; ++k) acc = fmaf(b[k], sW3r[k], acc);
    out[ig] = acc;
}

extern "C" void kernel_launch(void* const* d_in, const int* in_sizes, int n_in,
                              void* d_out, int out_size, void* d_ws, size_t ws_size,
                              hipStream_t stream) {
    const float* x   = (const float*)d_in[0];
    const float* ew  = (const float*)d_in[1];
    const float* Wu1 = (const float*)d_in[2];
    const float* bu1 = (const float*)d_in[3];
    const float* Wu2 = (const float*)d_in[4];
    const float* bu2 = (const float*)d_in[5];
    const float* Wu3 = (const float*)d_in[6];
    const float* bu3 = (const float*)d_in[7];
    const float* Wr1 = (const float*)d_in[8];
    const float* br1 = (const float*)d_in[9];
    const float* Wr2 = (const float*)d_in[10];
    const float* br2 = (const float*)d_in[11];
    const float* Wr3 = (const float*)d_in[12];
    const float* br3 = (const float*)d_in[13];
    const int* edges = (const int*)d_in[14];
    const int* gen   = (const int*)d_in[15];

    const int n    = in_sizes[0] / 8;
    const int E    = in_sizes[1] / 4;
    const int ngen = in_sizes[15];
    const int* dst = edges;      // node_idx (segment ids)
    const int* src = edges + E;  // nbr_idx (gather source)
    float* out = (float*)d_out;

    const int nblk  = (n + 63) / 64;
    const int npad  = nblk * 64;
    const int nbins = (n + NPB - 1) / NPB;   // 196 for n=100k (<=256 required)

    // workspace layout (256B aligned slabs)
    char* ws = (char*)d_ws;
    size_t off = 0;
    auto alloc = [&](size_t bytes) -> char* {
        char* p = ws + off;
        off = (off + bytes + 255) & ~(size_t)255;
        return p;
    };
    int* row_start = (int*)alloc((size_t)(n + 1) * 4);
    int* binCnt    = (int*)alloc(256 * 4);
    int* binStart  = (int*)alloc(256 * 4);
    int* snbr      = (int*)alloc((size_t)E * 4);
    int* seid      = (int*)alloc((size_t)E * 4);
    // union region: staged (CSR build only) / reps+weights (after binB)
    char* ubase = ws + off;
    size_t staged_sz = (size_t)nbins * BIN_CAP * 8;
    int2* staged  = (int2*)ubase;
    half_t* repsA = (half_t*)ubase;
    half_t* repsB = repsA + (size_t)npad * 32;
    half_t* Wt1   = repsB + (size_t)npad * 32;
    half_t* Wt2   = Wt1 + 32768;
    half_t* Wt3   = Wt2 + 32768;
    (void)staged_sz; (void)ws_size;

    // ---- CSR build (binned) ----
    hipMemsetAsync(binCnt, 0, 256 * 4, stream);
    int nblkA = (E + 8191) / 8192;
    k_binA<<<nblkA, 256, 0, stream>>>(dst, src, binCnt, staged, E, nbins);
    k_scanN<<<1, 256, 0, stream>>>(binCnt, binStart, row_start, nbins, n, E);
    k_binB<<<nbins, 512, 0, stream>>>(binCnt, binStart, staged, row_start, snbr, seid, n);

    // ---- weights + prepare (staged is dead from here; reps overlay it) ----
    k_wprep<<<272, 256, 0, stream>>>(Wu1, Wu2, Wu3, Wt1, Wt2, Wt3);
    k_prepare<<<(n + 255) / 256, 256, 0, stream>>>(x, ew, row_start, seid, repsA, n);

    half_t* cur = repsA;
    half_t* nxt = repsB;
    for (int it = 0; it < 3; ++it) {
        k_mlp<<<nblk, 512, 0, stream>>>(cur, row_start, snbr, Wt1, Wt2, Wt3,
                                        bu1, bu2, bu3, nxt, n);
        half_t* t = cur; cur = nxt; nxt = t;
    }

    k_readout<<<(ngen + 255) / 256, 256, 0, stream>>>(cur, gen, Wr1, br1, Wr2, br2,
                                                      Wr3, br3, out, ngen);
}

// Round 7
// 361.005 us; speedup vs baseline: 9.0415x; 1.1336x over previous
//
#include <hip/hip_runtime.h>
#include <cfloat>
#include <cmath>

// ---------------------------------------------------------------------------
// GNN message passing — fp16 MFMA, round 7.
//  R7 change (theory-first): k_mlp gather restructured for memory-level
//  parallelism. r6 counters: MfmaUtil 5.5%, VALUBusy 29%, hbm 8% -> gather is
//  latency-bound at ~14 rows in flight/CU (shfl-serialized, 4 nodes serial
//  per group). New layout: 16-lane subgroup per node; lane=(nb 0..3, ch 0..3)
//  reads 16B of neighbor nb's 64B row (4 lanes = 1 row, coalesced); idx via
//  direct per-lane snbr load (no ds_bpermute in the chain); 16 neighbors
//  statically unrolled per iteration -> 16 rows in flight per subgroup,
//  ~512/block. Cross-nb reduce = shfl_xor(4,8); epilogue writes 16B/lane
//  contiguous into sH.
//  Everything else unchanged from r6 (binned CSR, fused MFMA MLP, l2norm).
// MFMA mapping (verified r3-r6): D=A*B, A=W^T[nout][k], B=H[node][k]; D:
// col=lane&15=node, row=(lane>>4)*4+reg=nout.
// ---------------------------------------------------------------------------

typedef _Float16 half_t;
typedef _Float16 half8 __attribute__((ext_vector_type(8)));
typedef _Float16 half4_t __attribute__((ext_vector_type(4)));
typedef float f32x4 __attribute__((ext_vector_type(4)));

#define NPB 512        // nodes per bin (power of 2: bin = dst>>9)
#define BIN_CAP 10240  // slots per bin; mean fill ~8163, +23 sigma headroom

__device__ __forceinline__ float fast_tanh(float x) {
    // 1 - 2/(1+exp(2x)) via hw exp2 + rcp (1ulp): exact +-1 saturation.
    float e = __builtin_amdgcn_exp2f(x * 2.8853900817779268f);
    return 1.0f - 2.0f * __builtin_amdgcn_rcpf(1.0f + e);
}

__device__ __forceinline__ half_t cvt_clamp(float v) {
    return (half_t)fminf(fmaxf(v, -60000.f), 60000.f);
}

// ---------------- phase A: bin edges (coalesced staging) ----------------
__global__ __launch_bounds__(256) void k_binA(
    const int* __restrict__ dst, const int* __restrict__ src,
    int* __restrict__ binCnt, int2* __restrict__ staged, int E, int nbins) {
    __shared__ int cnt[256], base[256], cur[256];
    int t = threadIdx.x;
    cnt[t] = 0;
    cur[t] = 0;
    __syncthreads();
    int e0 = blockIdx.x * 8192;
#pragma unroll 4
    for (int i = 0; i < 32; ++i) {
        int e = e0 + i * 256 + t;
        if (e < E) atomicAdd(&cnt[dst[e] >> 9], 1);
    }
    __syncthreads();
    if (t < nbins && cnt[t] > 0) base[t] = atomicAdd(&binCnt[t], cnt[t]);
    __syncthreads();
#pragma unroll 4
    for (int i = 0; i < 32; ++i) {
        int e = e0 + i * 256 + t;
        if (e < E) {
            int d = dst[e];
            int b = d >> 9;
            int j = base[b] + atomicAdd(&cur[b], 1);
            if (j < BIN_CAP)  // statistically unreachable; guards OOB
                staged[(size_t)b * BIN_CAP + j] =
                    make_int2(src[e], ((d & (NPB - 1)) << 21) | e);
        }
    }
}

// ---------------- bin-count exclusive scan (nbins <= 256) ----------------
__global__ void k_scanN(const int* __restrict__ binCnt, int* __restrict__ binStart,
                        int* __restrict__ row_start, int nbins, int n, int E) {
    __shared__ int sh[256];
    int t = threadIdx.x;
    int v = (t < nbins) ? binCnt[t] : 0;
    sh[t] = v;
    __syncthreads();
    for (int s = 1; s < 256; s <<= 1) {
        int u = (t >= s) ? sh[t - s] : 0;
        __syncthreads();
        sh[t] += u;
        __syncthreads();
    }
    if (t < nbins) binStart[t] = sh[t] - v;
    if (t == 0) row_start[n] = E;
}

// ---------------- phase B: per-bin local CSR (LDS atomics/scan) ----------------
__global__ __launch_bounds__(512) void k_binB(
    const int* __restrict__ binCnt, const int* __restrict__ binStart,
    const int2* __restrict__ staged, int* __restrict__ row_start,
    int* __restrict__ snbr, int* __restrict__ seid, int n) {
    __shared__ int deg[NPB], cur[NPB], rsl[NPB];
    int t = threadIdx.x;
    int bin = blockIdx.x;
    int cntE = min(binCnt[bin], BIN_CAP);
    int pbase = binStart[bin];
    const int2* st = staged + (size_t)bin * BIN_CAP;
    deg[t] = 0;
    cur[t] = 0;
    __syncthreads();
    for (int i = t; i < cntE; i += 512)
        atomicAdd(&deg[(st[i].y >> 21) & (NPB - 1)], 1);
    __syncthreads();
    int own = deg[t];
    for (int s = 1; s < NPB; s <<= 1) {  // inclusive Hillis-Steele
        int u = (t >= s) ? deg[t - s] : 0;
        __syncthreads();
        deg[t] += u;
        __syncthreads();
    }
    int excl = deg[t] - own;
    rsl[t] = pbase + excl;
    int node = bin * NPB + t;
    if (node < n) row_start[node] = pbase + excl;
    __syncthreads();
    for (int i = t; i < cntE; i += 512) {
        int2 v = st[i];
        int dl = (v.y >> 21) & (NPB - 1);
        int p = rsl[dl] + atomicAdd(&cur[dl], 1);
        snbr[p] = v.x;
        seid[p] = v.y & 0x1FFFFF;
    }
}

// ---------------- prepare (fp32 stats -> reps fp16 [n][32]) ----------------
__global__ void k_prepare(const float* __restrict__ x, const float* __restrict__ ew,
                          const int* __restrict__ row_start, const int* __restrict__ seid,
                          half_t* __restrict__ reps, int n) {
    int v = blockIdx.x * 256 + threadIdx.x;
    if (v >= n) return;
    int s0 = row_start[v], s1 = row_start[v + 1];
    float4 s = {0.f, 0.f, 0.f, 0.f};
    float4 mx = {-INFINITY, -INFINITY, -INFINITY, -INFINITY};
    float4 mn = {INFINITY, INFINITY, INFINITY, INFINITY};
    const float4* ew4 = reinterpret_cast<const float4*>(ew);
    for (int e = s0; e < s1; ++e) {
        float4 w = ew4[seid[e]];
        s.x += w.x; s.y += w.y; s.z += w.z; s.w += w.w;
        mx.x = fmaxf(mx.x, w.x); mx.y = fmaxf(mx.y, w.y);
        mx.z = fmaxf(mx.z, w.z); mx.w = fmaxf(mx.w, w.w);
        mn.x = fminf(mn.x, w.x); mn.y = fminf(mn.y, w.y);
        mn.z = fminf(mn.z, w.z); mn.w = fminf(mn.w, w.w);
    }
    float cnt = fmaxf((float)(s1 - s0), 1.0f);
    if (s1 == s0) {
        mx = {-FLT_MAX, -FLT_MAX, -FLT_MAX, -FLT_MAX};
        mn = {FLT_MAX, FLT_MAX, FLT_MAX, FLT_MAX};
    }
    float4 mean = {s.x / cnt, s.y / cnt, s.z / cnt, s.w / cnt};
    const float4* x4 = reinterpret_cast<const float4*>(x);
    float4 x0 = x4[v * 2 + 0], x1 = x4[v * 2 + 1];

    half_t* o = &reps[(size_t)v * 32];
    half8 c0 = {cvt_clamp(x0.x), cvt_clamp(x0.y), cvt_clamp(x0.z), cvt_clamp(x0.w),
                cvt_clamp(x1.x), cvt_clamp(x1.y), cvt_clamp(x1.z), cvt_clamp(x1.w)};
    half8 c1 = {cvt_clamp(mean.x), cvt_clamp(mean.y), cvt_clamp(mean.z), cvt_clamp(mean.w),
                cvt_clamp(mx.x), cvt_clamp(mx.y), cvt_clamp(mx.z), cvt_clamp(mx.w)};
    half8 c2 = {cvt_clamp(mn.x), cvt_clamp(mn.y), cvt_clamp(mn.z), cvt_clamp(mn.w),
                cvt_clamp(s.x), cvt_clamp(s.y), cvt_clamp(s.z), cvt_clamp(s.w)};
    half8 c3 = {(half_t)0.f, (half_t)0.f, (half_t)0.f, (half_t)0.f,
                (half_t)0.f, (half_t)0.f, (half_t)0.f, (half_t)0.f};
    *(half8*)&o[0] = c0;
    *(half8*)&o[8] = c1;
    *(half8*)&o[16] = c2;
    *(half8*)&o[24] = c3;
}

// ---------------- weight prep: fp32 [k][n] -> fp16 [n][k] ----------------
__global__ void k_wprep(const float* __restrict__ Wu1, const float* __restrict__ Wu2,
                        const float* __restrict__ Wu3, half_t* __restrict__ Wt1,
                        half_t* __restrict__ Wt2, half_t* __restrict__ Wt3) {
    int i = blockIdx.x * 256 + threadIdx.x;
    if (i < 32768) {
        int nrow = i >> 7, k = i & 127;
        Wt1[i] = (half_t)Wu1[k * 256 + nrow];
    } else if (i < 65536) {
        int j = i - 32768;
        int nrow = j >> 8, k = j & 255;
        Wt2[j] = (half_t)Wu2[k * 128 + nrow];
    } else if (i < 69632) {
        int j = i - 65536;
        int nrow = j >> 7, k = j & 127;
        Wt3[j] = (half_t)Wu3[k * 32 + nrow];
    }
}

// ---------------- fused iter: MLP-gather + 3-layer MFMA MLP + l2norm ----------------
#define MFMA16(a, b, c) __builtin_amdgcn_mfma_f32_16x16x32_f16((a), (b), (c), 0, 0, 0)

__global__ __launch_bounds__(512, 4) void k_mlp(
    const half_t* __restrict__ reps_in,
    const int* __restrict__ row_start, const int* __restrict__ snbr,
    const half_t* __restrict__ Wt1, const half_t* __restrict__ Wt2,
    const half_t* __restrict__ Wt3,
    const float* __restrict__ bu1, const float* __restrict__ bu2,
    const float* __restrict__ bu3,
    half_t* __restrict__ reps_out, int n) {
    __shared__ half_t sH[64 * 136];    // H[64][128] (+8 pad); later h2[64][128]
    __shared__ half_t sh1[64 * 264];   // h1[64][256] (+8 pad)

    const int tid = threadIdx.x;
    const int w   = tid >> 6;          // wave 0..7
    const int l15 = tid & 15;
    const int lk  = (tid & 63) >> 4;   // k-group 0..3
    const int node0 = blockIdx.x * 64;

    // ---- gather: 32 subgroups of 16 lanes; each subgroup one node (x2) ----
    // lane = (nb 0..3, ch 0..3): 4 lanes read one 64B neighbor row coalesced;
    // 16 neighbors statically unrolled per iteration -> 16 rows in flight per
    // subgroup. idx via direct per-lane load (no ds_bpermute in the chain).
    {
        const int sg = tid >> 4;   // subgroup 0..31
        const int l  = tid & 15;   // lane in subgroup
        const int nb = l >> 2;     // neighbor slot 0..3
        const int ch = l & 3;      // 16B chunk of row

        for (int i = 0; i < 2; ++i) {
            int nl = i * 32 + sg;
            int node = node0 + nl;
            float s[8], mx[8], mn[8];
#pragma unroll
            for (int f = 0; f < 8; ++f) { s[f] = 0.f; mx[f] = -INFINITY; mn[f] = INFINITY; }
            int d0 = 0, d1 = 0;
            if (node < n) { d0 = row_start[node]; d1 = row_start[node + 1]; }

            for (int e = d0; e < d1; e += 16) {
                int ii0, ii1, ii2, ii3;
                bool v0, v1, v2, v3;
                {
                    int e0 = e + nb,      e1 = e + 4 + nb;
                    int e2 = e + 8 + nb,  e3 = e + 12 + nb;
                    v0 = e0 < d1; v1 = e1 < d1; v2 = e2 < d1; v3 = e3 < d1;
                    ii0 = snbr[min(e0, d1 - 1)];
                    ii1 = snbr[min(e1, d1 - 1)];
                    ii2 = snbr[min(e2, d1 - 1)];
                    ii3 = snbr[min(e3, d1 - 1)];
                }
                half8 r0 = *(const half8*)&reps_in[(size_t)ii0 * 32 + ch * 8];
                half8 r1 = *(const half8*)&reps_in[(size_t)ii1 * 32 + ch * 8];
                half8 r2 = *(const half8*)&reps_in[(size_t)ii2 * 32 + ch * 8];
                half8 r3 = *(const half8*)&reps_in[(size_t)ii3 * 32 + ch * 8];
#pragma unroll
                for (int f = 0; f < 8; ++f) {
                    float a0 = (float)r0[f];
                    if (v0) { s[f] += a0; mx[f] = fmaxf(mx[f], a0); mn[f] = fminf(mn[f], a0); }
                }
#pragma unroll
                for (int f = 0; f < 8; ++f) {
                    float a1 = (float)r1[f];
                    if (v1) { s[f] += a1; mx[f] = fmaxf(mx[f], a1); mn[f] = fminf(mn[f], a1); }
                }
#pragma unroll
                for (int f = 0; f < 8; ++f) {
                    float a2 = (float)r2[f];
                    if (v2) { s[f] += a2; mx[f] = fmaxf(mx[f], a2); mn[f] = fminf(mn[f], a2); }
                }
#pragma unroll
                for (int f = 0; f < 8; ++f) {
                    float a3 = (float)r3[f];
                    if (v3) { s[f] += a3; mx[f] = fmaxf(mx[f], a3); mn[f] = fminf(mn[f], a3); }
                }
            }
            // reduce across the 4 nb slots (xor strides 4, 8 inside subgroup)
#pragma unroll
            for (int f = 0; f < 8; ++f) {
                s[f] += __shfl_xor(s[f], 4);
                mx[f] = fmaxf(mx[f], __shfl_xor(mx[f], 4));
                mn[f] = fminf(mn[f], __shfl_xor(mn[f], 4));
                s[f] += __shfl_xor(s[f], 8);
                mx[f] = fmaxf(mx[f], __shfl_xor(mx[f], 8));
                mn[f] = fminf(mn[f], __shfl_xor(mn[f], 8));
            }
            float cnt = fmaxf((float)(d1 - d0), 1.f);
            // lane role: nb selects segment {r, mean, max, min}; empty-degree
            // sentinels (+-inf) clamp to +-60000 (same as r6's -FLT_MAX path).
            half8 o;
            if (nb == 0) {
                if (node < n) {
                    o = *(const half8*)&reps_in[(size_t)node * 32 + ch * 8];
                } else {
#pragma unroll
                    for (int f = 0; f < 8; ++f) o[f] = (half_t)0.f;
                }
            } else if (nb == 1) {
                float rc = __builtin_amdgcn_rcpf(cnt);
#pragma unroll
                for (int f = 0; f < 8; ++f) o[f] = cvt_clamp(s[f] * rc);
            } else if (nb == 2) {
#pragma unroll
                for (int f = 0; f < 8; ++f) o[f] = cvt_clamp(mx[f]);
            } else {
#pragma unroll
                for (int f = 0; f < 8; ++f) o[f] = cvt_clamp(mn[f]);
            }
            *(half8*)&sH[nl * 136 + l * 8] = o;   // l*8 = nb*32 + ch*8
        }
    }
    __syncthreads();

    // ---- GEMM1: h1 = tanh(H @ W1 + b1); wave owns nout [w*32, w*32+32) ----
    {
        half8 a0[4], a1[4];
#pragma unroll
        for (int ks = 0; ks < 4; ++ks) {
            a0[ks] = *(const half8*)&Wt1[(w * 32 + l15) * 128 + ks * 32 + lk * 8];
            a1[ks] = *(const half8*)&Wt1[(w * 32 + 16 + l15) * 128 + ks * 32 + lk * 8];
        }
        f32x4 bv0 = *(const f32x4*)&bu1[w * 32 + lk * 4];
        f32x4 bv1 = *(const f32x4*)&bu1[w * 32 + 16 + lk * 4];
#pragma unroll
        for (int nt = 0; nt < 4; ++nt) {
            const half_t* hrow = &sH[(nt * 16 + l15) * 136 + lk * 8];
            half8 b0 = *(const half8*)&hrow[0];
            half8 b1 = *(const half8*)&hrow[32];
            half8 b2 = *(const half8*)&hrow[64];
            half8 b3 = *(const half8*)&hrow[96];
            f32x4 acc0 = {0.f, 0.f, 0.f, 0.f}, acc1 = {0.f, 0.f, 0.f, 0.f};
            acc0 = MFMA16(a0[0], b0, acc0);
            acc0 = MFMA16(a0[1], b1, acc0);
            acc0 = MFMA16(a0[2], b2, acc0);
            acc0 = MFMA16(a0[3], b3, acc0);
            acc1 = MFMA16(a1[0], b0, acc1);
            acc1 = MFMA16(a1[1], b1, acc1);
            acc1 = MFMA16(a1[2], b2, acc1);
            acc1 = MFMA16(a1[3], b3, acc1);
            int node = nt * 16 + l15;
            half4_t o0, o1;
#pragma unroll
            for (int r = 0; r < 4; ++r) {
                o0[r] = (half_t)fast_tanh(acc0[r] + bv0[r]);
                o1[r] = (half_t)fast_tanh(acc1[r] + bv1[r]);
            }
            *(half4_t*)&sh1[node * 264 + w * 32 + lk * 4] = o0;
            *(half4_t*)&sh1[node * 264 + w * 32 + 16 + lk * 4] = o1;
        }
    }
    __syncthreads();

    // ---- GEMM2: h2 = tanh(h1 @ W2 + b2) -> overlay into sH (dead) ----
    {
        half8 a[8];
#pragma unroll
        for (int ks = 0; ks < 8; ++ks)
            a[ks] = *(const half8*)&Wt2[(w * 16 + l15) * 256 + ks * 32 + lk * 8];
        f32x4 bv = *(const f32x4*)&bu2[w * 16 + lk * 4];
#pragma unroll
        for (int nt = 0; nt < 4; ++nt) {
            f32x4 acc = {0.f, 0.f, 0.f, 0.f};
#pragma unroll
            for (int ks = 0; ks < 8; ++ks) {
                half8 b = *(const half8*)&sh1[(nt * 16 + l15) * 264 + ks * 32 + lk * 8];
                acc = MFMA16(a[ks], b, acc);
            }
            half4_t o;
#pragma unroll
            for (int r = 0; r < 4; ++r)
                o[r] = (half_t)fast_tanh(acc[r] + bv[r]);
            *(half4_t*)&sH[(nt * 16 + l15) * 136 + w * 16 + lk * 4] = o;
        }
    }
    __syncthreads();

    // ---- GEMM3 + l2norm: waves 0..3, wave w owns nodes [w*16,(w+1)*16) ----
    if (w < 4) {
        half8 a0[4], a1[4], b[4];
#pragma unroll
        for (int ks = 0; ks < 4; ++ks) {
            a0[ks] = *(const half8*)&Wt3[l15 * 128 + ks * 32 + lk * 8];
            a1[ks] = *(const half8*)&Wt3[(16 + l15) * 128 + ks * 32 + lk * 8];
            b[ks]  = *(const half8*)&sH[(w * 16 + l15) * 136 + ks * 32 + lk * 8];
        }
        f32x4 acc0 = {0.f, 0.f, 0.f, 0.f}, acc1 = {0.f, 0.f, 0.f, 0.f};
#pragma unroll
        for (int ks = 0; ks < 4; ++ks) {
            acc0 = MFMA16(a0[ks], b[ks], acc0);
            acc1 = MFMA16(a1[ks], b[ks], acc1);
        }
        f32x4 bv0 = *(const f32x4*)&bu3[lk * 4];
        f32x4 bv1 = *(const f32x4*)&bu3[16 + lk * 4];
        float v0[4], v1[4];
        float ss = 0.f;
#pragma unroll
        for (int r = 0; r < 4; ++r) {
            v0[r] = fast_tanh(acc0[r] + bv0[r]);
            v1[r] = fast_tanh(acc1[r] + bv1[r]);
            ss += v0[r] * v0[r] + v1[r] * v1[r];
        }
        ss += __shfl_xor(ss, 16);
        ss += __shfl_xor(ss, 32);
        float sc = rsqrtf(fmaxf(ss, 1e-12f));
        int node = node0 + w * 16 + l15;
        if (node < n) {
            half4_t o0, o1;
#pragma unroll
            for (int r = 0; r < 4; ++r) {
                o0[r] = (half_t)(v0[r] * sc);
                o1[r] = (half_t)(v1[r] * sc);
            }
            *(half4_t*)&reps_out[(size_t)node * 32 + lk * 4] = o0;
            *(half4_t*)&reps_out[(size_t)node * 32 + 16 + lk * 4] = o1;
        }
    }
}

// ---------------- readout: gather generators (nan->0), 32->64->32->1 ----------------
__global__ __launch_bounds__(256) void k_readout(
    const half_t* __restrict__ reps, const int* __restrict__ gen,
    const float* __restrict__ Wr1, const float* __restrict__ br1,
    const float* __restrict__ Wr2, const float* __restrict__ br2,
    const float* __restrict__ Wr3, const float* __restrict__ br3,
    float* __restrict__ out, int ngen) {
    __shared__ float sW1[32 * 64];
    __shared__ float sW2[64 * 32];
    __shared__ float sb1[64];
    __shared__ float sb2[32];
    __shared__ float sW3r[32];
    __shared__ float sb3;
    int tid = threadIdx.x;
    for (int i = tid; i < 2048; i += 256) sW1[i] = Wr1[i];
    for (int i = tid; i < 2048; i += 256) sW2[i] = Wr2[i];
    if (tid < 64) sb1[tid] = br1[tid];
    if (tid < 32) sb2[tid] = br2[tid];
    if (tid < 32) sW3r[tid] = Wr3[tid];
    if (tid == 0) sb3 = br3[0];
    __syncthreads();
    int ig = blockIdx.x * 256 + tid;
    if (ig >= ngen) return;
    int node = gen[ig];
    float g[32];
#pragma unroll
    for (int q = 0; q < 4; ++q) {
        half8 v = *(const half8*)&reps[(size_t)node * 32 + q * 8];
#pragma unroll
        for (int r = 0; r < 8; ++r) {
            float f = (float)v[r];
            g[q * 8 + r] = (f != f) ? 0.f : f;
        }
    }
    float a[64];
#pragma unroll
    for (int o = 0; o < 64; ++o) {
        float acc = sb1[o];
#pragma unroll
        for (int k = 0; k < 32; ++k) acc = fmaf(g[k], sW1[k * 64 + o], acc);
        a[o] = fast_tanh(acc);
    }
    float b[32];
#pragma unroll
    for (int o = 0; o < 32; ++o) {
        float acc = sb2[o];
#pragma unroll
        for (int k = 0; k < 64; ++k) acc = fmaf(a[k], sW2[k * 32 + o], acc);
        b[o] = fast_tanh(acc);
    }
    float acc = sb3;
#pragma unroll
    for (int k = 0; k < 32; ++k) acc = fmaf(b[k], sW3r[k], acc);
    out[ig] = acc;
}

extern "C" void kernel_launch(void* const* d_in, const int* in_sizes, int n_in,
                              void* d_out, int out_size, void* d_ws, size_t ws_size,
                              hipStream_t stream) {
    const float* x   = (const float*)d_in[0];
    const float* ew  = (const float*)d_in[1];
    const float* Wu1 = (const float*)d_in[2];
    const float* bu1 = (const float*)d_in[3];
    const float* Wu2 = (const float*)d_in[4];
    const float* bu2 = (const float*)d_in[5];
    const float* Wu3 = (const float*)d_in[6];
    const float* bu3 = (const float*)d_in[7];
    const float* Wr1 = (const float*)d_in[8];
    const float* br1 = (const float*)d_in[9];
    const float* Wr2 = (const float*)d_in[10];
    const float* br2 = (const float*)d_in[11];
    const float* Wr3 = (const float*)d_in[12];
    const float* br3 = (const float*)d_in[13];
    const int* edges = (const int*)d_in[14];
    const int* gen   = (const int*)d_in[15];

    const int n    = in_sizes[0] / 8;
    const int E    = in_sizes[1] / 4;
    const int ngen = in_sizes[15];
    const int* dst = edges;      // node_idx (segment ids)
    const int* src = edges + E;  // nbr_idx (gather source)
    float* out = (float*)d_out;

    const int nblk  = (n + 63) / 64;
    const int npad  = nblk * 64;
    const int nbins = (n + NPB - 1) / NPB;   // 196 for n=100k (<=256 required)

    // workspace layout (256B aligned slabs)
    char* ws = (char*)d_ws;
    size_t off = 0;
    auto alloc = [&](size_t bytes) -> char* {
        char* p = ws + off;
        off = (off + bytes + 255) & ~(size_t)255;
        return p;
    };
    int* row_start = (int*)alloc((size_t)(n + 1) * 4);
    int* binCnt    = (int*)alloc(256 * 4);
    int* binStart  = (int*)alloc(256 * 4);
    int* snbr      = (int*)alloc((size_t)E * 4);
    int* seid      = (int*)alloc((size_t)E * 4);
    // union region: staged (CSR build only) / reps+weights (after binB)
    char* ubase = ws + off;
    int2* staged  = (int2*)ubase;
    half_t* repsA = (half_t*)ubase;
    half_t* repsB = repsA + (size_t)npad * 32;
    half_t* Wt1   = repsB + (size_t)npad * 32;
    half_t* Wt2   = Wt1 + 32768;
    half_t* Wt3   = Wt2 + 32768;
    (void)ws_size;

    // ---- CSR build (binned) ----
    hipMemsetAsync(binCnt, 0, 256 * 4, stream);
    int nblkA = (E + 8191) / 8192;
    k_binA<<<nblkA, 256, 0, stream>>>(dst, src, binCnt, staged, E, nbins);
    k_scanN<<<1, 256, 0, stream>>>(binCnt, binStart, row_start, nbins, n, E);
    k_binB<<<nbins, 512, 0, stream>>>(binCnt, binStart, staged, row_start, snbr, seid, n);

    // ---- weights + prepare (staged is dead from here; reps overlay it) ----
    k_wprep<<<272, 256, 0, stream>>>(Wu1, Wu2, Wu3, Wt1, Wt2, Wt3);
    k_prepare<<<(n + 255) / 256, 256, 0, stream>>>(x, ew, row_start, seid, repsA, n);

    half_t* cur = repsA;
    half_t* nxt = repsB;
    for (int it = 0; it < 3; ++it) {
        k_mlp<<<nblk, 512, 0, stream>>>(cur, row_start, snbr, Wt1, Wt2, Wt3,
                                        bu1, bu2, bu3, nxt, n);
        half_t* t = cur; cur = nxt; nxt = t;
    }

    k_readout<<<(ngen + 255) / 256, 256, 0, stream>>>(cur, gen, Wr1, br1, Wr2, br2,
                                                      Wr3, br3, out, ngen);
}

// Round 8
// 342.223 us; speedup vs baseline: 9.5378x; 1.0549x over previous
//
#include <hip/hip_runtime.h>
#include <cfloat>
#include <cmath>

// ---------------------------------------------------------------------------
// GNN message passing — fp16 MFMA, round 8.
//  R8 changes (theory-first; r7 evidence: FETCH 54MB = reps re-fetched by all
//  8 XCDs each dispatch -> zero L2 reuse; gather chain = idx(700cy) -> rows
//  (700cy) serial; occupancy 33%):
//   1. Edge-index LDS stage: block's CSR range is contiguous -> one coalesced
//      burst into LDS (aliased over sh1c, dead until GEMM1). Row loads now
//      depend on ~40cy LDS reads, not 700cy L3 reads.
//   2. Split-K GEMM1/GEMM2 (two 128-col h1 chunks through one buffer,
//      accumulation order bit-identical) -> LDS 51.2->34.8KB -> 4 blocks/CU;
//      __launch_bounds__(512,8) caps VGPR at 64.
//   3. nontemporal snbr loads + reps_out stores: reps owns the L2.
//   4. k_prepare folded into k_binB (LDS fp32-sum + int-bit max/min atomics;
//      ew>=0 makes int-bit compare monotone) -> seid array deleted.
// MFMA mapping (verified r3-r7): D=A*B, A=W^T[nout][k], B=H[node][k]; D:
// col=lane&15=node, row=(lane>>4)*4+reg=nout.
// ---------------------------------------------------------------------------

typedef _Float16 half_t;
typedef _Float16 half8 __attribute__((ext_vector_type(8)));
typedef _Float16 half4_t __attribute__((ext_vector_type(4)));
typedef float f32x4 __attribute__((ext_vector_type(4)));

#define NPB 512        // nodes per bin (power of 2: bin = dst>>9)
#define BIN_CAP 10240  // slots per bin; mean fill ~8163, +23 sigma headroom
#define IDXCAP 4352    // LDS idx slots per k_mlp block (mean 1024, +100 sigma)

__device__ __forceinline__ float fast_tanh(float x) {
    float e = __builtin_amdgcn_exp2f(x * 2.8853900817779268f);
    return 1.0f - 2.0f * __builtin_amdgcn_rcpf(1.0f + e);
}

__device__ __forceinline__ half_t cvt_clamp(float v) {
    return (half_t)fminf(fmaxf(v, -60000.f), 60000.f);
}

// ---------------- phase A: bin edges (coalesced staging) ----------------
__global__ __launch_bounds__(256) void k_binA(
    const int* __restrict__ dst, const int* __restrict__ src,
    int* __restrict__ binCnt, int2* __restrict__ staged, int E, int nbins) {
    __shared__ int cnt[256], base[256], cur[256];
    int t = threadIdx.x;
    cnt[t] = 0;
    cur[t] = 0;
    __syncthreads();
    int e0 = blockIdx.x * 8192;
#pragma unroll 4
    for (int i = 0; i < 32; ++i) {
        int e = e0 + i * 256 + t;
        if (e < E) atomicAdd(&cnt[dst[e] >> 9], 1);
    }
    __syncthreads();
    if (t < nbins && cnt[t] > 0) base[t] = atomicAdd(&binCnt[t], cnt[t]);
    __syncthreads();
#pragma unroll 4
    for (int i = 0; i < 32; ++i) {
        int e = e0 + i * 256 + t;
        if (e < E) {
            int d = dst[e];
            int b = d >> 9;
            int j = base[b] + atomicAdd(&cur[b], 1);
            if (j < BIN_CAP)
                staged[(size_t)b * BIN_CAP + j] =
                    make_int2(src[e], ((d & (NPB - 1)) << 21) | e);
        }
    }
}

// ---------------- bin-count exclusive scan (nbins <= 256) ----------------
__global__ void k_scanN(const int* __restrict__ binCnt, int* __restrict__ binStart,
                        int* __restrict__ row_start, int nbins, int n, int E) {
    __shared__ int sh[256];
    int t = threadIdx.x;
    int v = (t < nbins) ? binCnt[t] : 0;
    sh[t] = v;
    __syncthreads();
    for (int s = 1; s < 256; s <<= 1) {
        int u = (t >= s) ? sh[t - s] : 0;
        __syncthreads();
        sh[t] += u;
        __syncthreads();
    }
    if (t < nbins) binStart[t] = sh[t] - v;
    if (t == 0) row_start[n] = E;
}

// ---------------- phase B: per-bin CSR + edge-weight stats + reps ----------------
__global__ __launch_bounds__(512) void k_binB(
    const int* __restrict__ binCnt, const int* __restrict__ binStart,
    const int2* __restrict__ staged, const float* __restrict__ x,
    const float* __restrict__ ew,
    int* __restrict__ row_start, int* __restrict__ snbr,
    half_t* __restrict__ reps, int n) {
    __shared__ int deg[NPB], cur[NPB], rsl[NPB];
    __shared__ float ssum[NPB * 4];
    __shared__ int smax[NPB * 4], smin[NPB * 4];   // float bits; ew >= 0
    int t = threadIdx.x;
    int bin = blockIdx.x;
    int cntE = min(binCnt[bin], BIN_CAP);
    int pbase = binStart[bin];
    const int2* st = staged + (size_t)bin * BIN_CAP;
    const float4* ew4 = reinterpret_cast<const float4*>(ew);

    deg[t] = 0;
    cur[t] = 0;
    for (int i = t; i < NPB * 4; i += 512) {
        ssum[i] = 0.f;
        smax[i] = 0;                 // ew >= 0: 0-bits = 0.0f lower bound
        smin[i] = 0x7f7fffff;        // FLT_MAX bits
    }
    __syncthreads();

    // pass 1: degree count + edge-weight stats
    for (int i = t; i < cntE; i += 512) {
        int2 v = st[i];
        int dl = (v.y >> 21) & (NPB - 1);
        atomicAdd(&deg[dl], 1);
        float4 w = ew4[v.y & 0x1FFFFF];
        atomicAdd(&ssum[dl * 4 + 0], w.x);
        atomicAdd(&ssum[dl * 4 + 1], w.y);
        atomicAdd(&ssum[dl * 4 + 2], w.z);
        atomicAdd(&ssum[dl * 4 + 3], w.w);
        atomicMax(&smax[dl * 4 + 0], __float_as_int(w.x));
        atomicMax(&smax[dl * 4 + 1], __float_as_int(w.y));
        atomicMax(&smax[dl * 4 + 2], __float_as_int(w.z));
        atomicMax(&smax[dl * 4 + 3], __float_as_int(w.w));
        atomicMin(&smin[dl * 4 + 0], __float_as_int(w.x));
        atomicMin(&smin[dl * 4 + 1], __float_as_int(w.y));
        atomicMin(&smin[dl * 4 + 2], __float_as_int(w.z));
        atomicMin(&smin[dl * 4 + 3], __float_as_int(w.w));
    }
    __syncthreads();

    int own = deg[t];
    for (int s = 1; s < NPB; s <<= 1) {   // inclusive Hillis-Steele scan
        int u = (t >= s) ? deg[t - s] : 0;
        __syncthreads();
        deg[t] += u;
        __syncthreads();
    }
    int excl = deg[t] - own;
    rsl[t] = pbase + excl;
    int node = bin * NPB + t;
    if (node < n) row_start[node] = pbase + excl;
    __syncthreads();

    // scatter pass: snbr only
    for (int i = t; i < cntE; i += 512) {
        int2 v = st[i];
        int dl = (v.y >> 21) & (NPB - 1);
        int p = rsl[dl] + atomicAdd(&cur[dl], 1);
        snbr[p] = v.x;
    }

    // reps row: [x(8), mean(4), max(4), min(4), sum(4), 0(8)] in fp16
    if (node < n) {
        float cnt = fmaxf((float)own, 1.0f);
        float rc = __builtin_amdgcn_rcpf(cnt);
        float sm0 = ssum[t * 4 + 0], sm1 = ssum[t * 4 + 1];
        float sm2 = ssum[t * 4 + 2], sm3 = ssum[t * 4 + 3];
        float mx0, mx1, mx2, mx3, mn0, mn1, mn2, mn3;
        if (own == 0) {
            mx0 = mx1 = mx2 = mx3 = -FLT_MAX;
            mn0 = mn1 = mn2 = mn3 = FLT_MAX;
        } else {
            mx0 = __int_as_float(smax[t * 4 + 0]);
            mx1 = __int_as_float(smax[t * 4 + 1]);
            mx2 = __int_as_float(smax[t * 4 + 2]);
            mx3 = __int_as_float(smax[t * 4 + 3]);
            mn0 = __int_as_float(smin[t * 4 + 0]);
            mn1 = __int_as_float(smin[t * 4 + 1]);
            mn2 = __int_as_float(smin[t * 4 + 2]);
            mn3 = __int_as_float(smin[t * 4 + 3]);
        }
        const float4* x4 = reinterpret_cast<const float4*>(x);
        float4 x0 = x4[node * 2 + 0], x1 = x4[node * 2 + 1];
        half_t* o = &reps[(size_t)node * 32];
        half8 c0 = {cvt_clamp(x0.x), cvt_clamp(x0.y), cvt_clamp(x0.z), cvt_clamp(x0.w),
                    cvt_clamp(x1.x), cvt_clamp(x1.y), cvt_clamp(x1.z), cvt_clamp(x1.w)};
        half8 c1 = {cvt_clamp(sm0 * rc), cvt_clamp(sm1 * rc), cvt_clamp(sm2 * rc), cvt_clamp(sm3 * rc),
                    cvt_clamp(mx0), cvt_clamp(mx1), cvt_clamp(mx2), cvt_clamp(mx3)};
        half8 c2 = {cvt_clamp(mn0), cvt_clamp(mn1), cvt_clamp(mn2), cvt_clamp(mn3),
                    cvt_clamp(sm0), cvt_clamp(sm1), cvt_clamp(sm2), cvt_clamp(sm3)};
        half8 c3 = {(half_t)0.f, (half_t)0.f, (half_t)0.f, (half_t)0.f,
                    (half_t)0.f, (half_t)0.f, (half_t)0.f, (half_t)0.f};
        *(half8*)&o[0] = c0;
        *(half8*)&o[8] = c1;
        *(half8*)&o[16] = c2;
        *(half8*)&o[24] = c3;
    }
}

// ---------------- weight prep: fp32 [k][n] -> fp16 [n][k] ----------------
__global__ void k_wprep(const float* __restrict__ Wu1, const float* __restrict__ Wu2,
                        const float* __restrict__ Wu3, half_t* __restrict__ Wt1,
                        half_t* __restrict__ Wt2, half_t* __restrict__ Wt3) {
    int i = blockIdx.x * 256 + threadIdx.x;
    if (i < 32768) {
        int nrow = i >> 7, k = i & 127;
        Wt1[i] = (half_t)Wu1[k * 256 + nrow];
    } else if (i < 65536) {
        int j = i - 32768;
        int nrow = j >> 8, k = j & 255;
        Wt2[j] = (half_t)Wu2[k * 128 + nrow];
    } else if (i < 69632) {
        int j = i - 65536;
        int nrow = j >> 7, k = j & 127;
        Wt3[j] = (half_t)Wu3[k * 32 + nrow];
    }
}

// ---------------- fused iter: LDS-idx gather + split-K MFMA MLP + l2norm ----------------
#define MFMA16(a, b, c) __builtin_amdgcn_mfma_f32_16x16x32_f16((a), (b), (c), 0, 0, 0)

__global__ __launch_bounds__(512, 8) void k_mlp(
    const half_t* __restrict__ reps_in,
    const int* __restrict__ row_start, const int* __restrict__ snbr,
    const half_t* __restrict__ Wt1, const half_t* __restrict__ Wt2,
    const half_t* __restrict__ Wt3,
    const float* __restrict__ bu1, const float* __restrict__ bu2,
    const float* __restrict__ bu3,
    half_t* __restrict__ reps_out, int n) {
    __shared__ half_t sH[64 * 136];     // H[64][128]; later h2[64][128]
    __shared__ half_t sh1c[64 * 136];   // idx stage, then h1 chunk [64][128]
    int* sIdx = (int*)sh1c;             // 4352 int slots

    const int tid = threadIdx.x;
    const int w   = tid >> 6;
    const int l15 = tid & 15;
    const int lk  = (tid & 63) >> 4;
    const int node0 = blockIdx.x * 64;

    // ---- idx stage: block's CSR range is contiguous -> coalesced LDS burst ----
    const int nodeEnd = min(node0 + 64, n);
    const int d0blk = row_start[node0];
    const int ecnt = row_start[nodeEnd] - d0blk;
    const bool lds_ok = (ecnt <= IDXCAP);
    if (lds_ok) {
        for (int i = tid; i < ecnt; i += 512)
            sIdx[i] = __builtin_nontemporal_load(&snbr[d0blk + i]);
    }
    __syncthreads();

    // ---- gather: 32 subgroups of 16 lanes; lane=(nb,ch); 16 rows in flight ----
    {
        const int sg = tid >> 4;
        const int l  = tid & 15;
        const int nb = l >> 2;
        const int ch = l & 3;

        for (int i = 0; i < 2; ++i) {
            int nl = i * 32 + sg;
            int node = node0 + nl;
            float s[8], mx[8], mn[8];
#pragma unroll
            for (int f = 0; f < 8; ++f) { s[f] = 0.f; mx[f] = -INFINITY; mn[f] = INFINITY; }
            int d0 = 0, d1 = 0;
            if (node < n) { d0 = row_start[node]; d1 = row_start[node + 1]; }

            for (int e = d0; e < d1; e += 16) {
                int e0 = e + nb, e1 = e + 4 + nb, e2 = e + 8 + nb, e3 = e + 12 + nb;
                bool v0 = e0 < d1, v1 = e1 < d1, v2 = e2 < d1, v3 = e3 < d1;
                int ii0, ii1, ii2, ii3;
                if (lds_ok) {
                    ii0 = sIdx[min(e0, d1 - 1) - d0blk];
                    ii1 = sIdx[min(e1, d1 - 1) - d0blk];
                    ii2 = sIdx[min(e2, d1 - 1) - d0blk];
                    ii3 = sIdx[min(e3, d1 - 1) - d0blk];
                } else {
                    ii0 = snbr[min(e0, d1 - 1)];
                    ii1 = snbr[min(e1, d1 - 1)];
                    ii2 = snbr[min(e2, d1 - 1)];
                    ii3 = snbr[min(e3, d1 - 1)];
                }
                half8 r0 = *(const half8*)&reps_in[(size_t)ii0 * 32 + ch * 8];
                half8 r1 = *(const half8*)&reps_in[(size_t)ii1 * 32 + ch * 8];
                half8 r2 = *(const half8*)&reps_in[(size_t)ii2 * 32 + ch * 8];
                half8 r3 = *(const half8*)&reps_in[(size_t)ii3 * 32 + ch * 8];
#pragma unroll
                for (int f = 0; f < 8; ++f) {
                    float a0 = (float)r0[f];
                    if (v0) { s[f] += a0; mx[f] = fmaxf(mx[f], a0); mn[f] = fminf(mn[f], a0); }
                }
#pragma unroll
                for (int f = 0; f < 8; ++f) {
                    float a1 = (float)r1[f];
                    if (v1) { s[f] += a1; mx[f] = fmaxf(mx[f], a1); mn[f] = fminf(mn[f], a1); }
                }
#pragma unroll
                for (int f = 0; f < 8; ++f) {
                    float a2 = (float)r2[f];
                    if (v2) { s[f] += a2; mx[f] = fmaxf(mx[f], a2); mn[f] = fminf(mn[f], a2); }
                }
#pragma unroll
                for (int f = 0; f < 8; ++f) {
                    float a3 = (float)r3[f];
                    if (v3) { s[f] += a3; mx[f] = fmaxf(mx[f], a3); mn[f] = fminf(mn[f], a3); }
                }
            }
#pragma unroll
            for (int f = 0; f < 8; ++f) {
                s[f] += __shfl_xor(s[f], 4);
                mx[f] = fmaxf(mx[f], __shfl_xor(mx[f], 4));
                mn[f] = fminf(mn[f], __shfl_xor(mn[f], 4));
                s[f] += __shfl_xor(s[f], 8);
                mx[f] = fmaxf(mx[f], __shfl_xor(mx[f], 8));
                mn[f] = fminf(mn[f], __shfl_xor(mn[f], 8));
            }
            float cnt = fmaxf((float)(d1 - d0), 1.f);
            half8 o;
            if (nb == 0) {
                if (node < n) {
                    o = *(const half8*)&reps_in[(size_t)node * 32 + ch * 8];
                } else {
#pragma unroll
                    for (int f = 0; f < 8; ++f) o[f] = (half_t)0.f;
                }
            } else if (nb == 1) {
                float rc = __builtin_amdgcn_rcpf(cnt);
#pragma unroll
                for (int f = 0; f < 8; ++f) o[f] = cvt_clamp(s[f] * rc);
            } else if (nb == 2) {
#pragma unroll
                for (int f = 0; f < 8; ++f) o[f] = cvt_clamp(mx[f]);
            } else {
#pragma unroll
                for (int f = 0; f < 8; ++f) o[f] = cvt_clamp(mn[f]);
            }
            *(half8*)&sH[nl * 136 + l * 8] = o;
        }
    }
    __syncthreads();   // gather done; sIdx dead -> sh1c reusable

    // ---- split-K: 2 chunks of {GEMM1 128 cols -> GEMM2 partial} ----
    f32x4 acc2[4] = {{0.f, 0.f, 0.f, 0.f}, {0.f, 0.f, 0.f, 0.f},
                     {0.f, 0.f, 0.f, 0.f}, {0.f, 0.f, 0.f, 0.f}};
#pragma unroll
    for (int c = 0; c < 2; ++c) {
        // GEMM1 chunk c: wave w owns h1 cols [c*128 + w*16, +16)
        {
            half8 a[4];
#pragma unroll
            for (int ks = 0; ks < 4; ++ks)
                a[ks] = *(const half8*)&Wt1[(c * 128 + w * 16 + l15) * 128 + ks * 32 + lk * 8];
            f32x4 bv = *(const f32x4*)&bu1[c * 128 + w * 16 + lk * 4];
#pragma unroll
            for (int nt = 0; nt < 4; ++nt) {
                const half_t* hrow = &sH[(nt * 16 + l15) * 136 + lk * 8];
                half8 b0 = *(const half8*)&hrow[0];
                half8 b1 = *(const half8*)&hrow[32];
                half8 b2 = *(const half8*)&hrow[64];
                half8 b3 = *(const half8*)&hrow[96];
                f32x4 acc = {0.f, 0.f, 0.f, 0.f};
                acc = MFMA16(a[0], b0, acc);
                acc = MFMA16(a[1], b1, acc);
                acc = MFMA16(a[2], b2, acc);
                acc = MFMA16(a[3], b3, acc);
                half4_t o;
#pragma unroll
                for (int r = 0; r < 4; ++r)
                    o[r] = (half_t)fast_tanh(acc[r] + bv[r]);
                *(half4_t*)&sh1c[(nt * 16 + l15) * 136 + w * 16 + lk * 4] = o;
            }
        }
        __syncthreads();   // h1 chunk ready
        // GEMM2 partial: k in [c*128, c*128+128)
        {
            half8 a[4];
#pragma unroll
            for (int ks = 0; ks < 4; ++ks)
                a[ks] = *(const half8*)&Wt2[(w * 16 + l15) * 256 + c * 128 + ks * 32 + lk * 8];
#pragma unroll
            for (int nt = 0; nt < 4; ++nt) {
#pragma unroll
                for (int ks = 0; ks < 4; ++ks) {
                    half8 b = *(const half8*)&sh1c[(nt * 16 + l15) * 136 + ks * 32 + lk * 8];
                    acc2[nt] = MFMA16(a[ks], b, acc2[nt]);
                }
            }
        }
        __syncthreads();   // chunk reads done before overwrite / sH overlay
    }

    // ---- h2 = tanh(acc2 + b2) -> overlay into sH (dead after GEMM1) ----
    {
        f32x4 bv = *(const f32x4*)&bu2[w * 16 + lk * 4];
#pragma unroll
        for (int nt = 0; nt < 4; ++nt) {
            half4_t o;
#pragma unroll
            for (int r = 0; r < 4; ++r)
                o[r] = (half_t)fast_tanh(acc2[nt][r] + bv[r]);
            *(half4_t*)&sH[(nt * 16 + l15) * 136 + w * 16 + lk * 4] = o;
        }
    }
    __syncthreads();

    // ---- GEMM3 + l2norm: waves 0..3, wave w owns nodes [w*16,(w+1)*16) ----
    if (w < 4) {
        half8 a0[4], a1[4], b[4];
#pragma unroll
        for (int ks = 0; ks < 4; ++ks) {
            a0[ks] = *(const half8*)&Wt3[l15 * 128 + ks * 32 + lk * 8];
            a1[ks] = *(const half8*)&Wt3[(16 + l15) * 128 + ks * 32 + lk * 8];
            b[ks]  = *(const half8*)&sH[(w * 16 + l15) * 136 + ks * 32 + lk * 8];
        }
        f32x4 acc0 = {0.f, 0.f, 0.f, 0.f}, acc1 = {0.f, 0.f, 0.f, 0.f};
#pragma unroll
        for (int ks = 0; ks < 4; ++ks) {
            acc0 = MFMA16(a0[ks], b[ks], acc0);
            acc1 = MFMA16(a1[ks], b[ks], acc1);
        }
        f32x4 bv0 = *(const f32x4*)&bu3[lk * 4];
        f32x4 bv1 = *(const f32x4*)&bu3[16 + lk * 4];
        float v0[4], v1[4];
        float ss = 0.f;
#pragma unroll
        for (int r = 0; r < 4; ++r) {
            v0[r] = fast_tanh(acc0[r] + bv0[r]);
            v1[r] = fast_tanh(acc1[r] + bv1[r]);
            ss += v0[r] * v0[r] + v1[r] * v1[r];
        }
        ss += __shfl_xor(ss, 16);
        ss += __shfl_xor(ss, 32);
        float sc = rsqrtf(fmaxf(ss, 1e-12f));
        int node = node0 + w * 16 + l15;
        if (node < n) {
            half4_t o0, o1;
#pragma unroll
            for (int r = 0; r < 4; ++r) {
                o0[r] = (half_t)(v0[r] * sc);
                o1[r] = (half_t)(v1[r] * sc);
            }
            __builtin_nontemporal_store(o0, (half4_t*)&reps_out[(size_t)node * 32 + lk * 4]);
            __builtin_nontemporal_store(o1, (half4_t*)&reps_out[(size_t)node * 32 + 16 + lk * 4]);
        }
    }
}

// ---------------- readout: gather generators (nan->0), 32->64->32->1 ----------------
__global__ __launch_bounds__(256) void k_readout(
    const half_t* __restrict__ reps, const int* __restrict__ gen,
    const float* __restrict__ Wr1, const float* __restrict__ br1,
    const float* __restrict__ Wr2, const float* __restrict__ br2,
    const float* __restrict__ Wr3, const float* __restrict__ br3,
    float* __restrict__ out, int ngen) {
    __shared__ float sW1[32 * 64];
    __shared__ float sW2[64 * 32];
    __shared__ float sb1[64];
    __shared__ float sb2[32];
    __shared__ float sW3r[32];
    __shared__ float sb3;
    int tid = threadIdx.x;
    for (int i = tid; i < 2048; i += 256) sW1[i] = Wr1[i];
    for (int i = tid; i < 2048; i += 256) sW2[i] = Wr2[i];
    if (tid < 64) sb1[tid] = br1[tid];
    if (tid < 32) sb2[tid] = br2[tid];
    if (tid < 32) sW3r[tid] = Wr3[tid];
    if (tid == 0) sb3 = br3[0];
    __syncthreads();
    int ig = blockIdx.x * 256 + tid;
    if (ig >= ngen) return;
    int node = gen[ig];
    float g[32];
#pragma unroll
    for (int q = 0; q < 4; ++q) {
        half8 v = *(const half8*)&reps[(size_t)node * 32 + q * 8];
#pragma unroll
        for (int r = 0; r < 8; ++r) {
            float f = (float)v[r];
            g[q * 8 + r] = (f != f) ? 0.f : f;
        }
    }
    float a[64];
#pragma unroll
    for (int o = 0; o < 64; ++o) {
        float acc = sb1[o];
#pragma unroll
        for (int k = 0; k < 32; ++k) acc = fmaf(g[k], sW1[k * 64 + o], acc);
        a[o] = fast_tanh(acc);
    }
    float b[32];
#pragma unroll
    for (int o = 0; o < 32; ++o) {
        float acc = sb2[o];
#pragma unroll
        for (int k = 0; k < 64; ++k) acc = fmaf(a[k], sW2[k * 32 + o], acc);
        b[o] = fast_tanh(acc);
    }
    float acc = sb3;
#pragma unroll
    for (int k = 0; k < 32; ++k) acc = fmaf(b[k], sW3r[k], acc);
    out[ig] = acc;
}

extern "C" void kernel_launch(void* const* d_in, const int* in_sizes, int n_in,
                              void* d_out, int out_size, void* d_ws, size_t ws_size,
                              hipStream_t stream) {
    const float* x   = (const float*)d_in[0];
    const float* ew  = (const float*)d_in[1];
    const float* Wu1 = (const float*)d_in[2];
    const float* bu1 = (const float*)d_in[3];
    const float* Wu2 = (const float*)d_in[4];
    const float* bu2 = (const float*)d_in[5];
    const float* Wu3 = (const float*)d_in[6];
    const float* bu3 = (const float*)d_in[7];
    const float* Wr1 = (const float*)d_in[8];
    const float* br1 = (const float*)d_in[9];
    const float* Wr2 = (const float*)d_in[10];
    const float* br2 = (const float*)d_in[11];
    const float* Wr3 = (const float*)d_in[12];
    const float* br3 = (const float*)d_in[13];
    const int* edges = (const int*)d_in[14];
    const int* gen   = (const int*)d_in[15];

    const int n    = in_sizes[0] / 8;
    const int E    = in_sizes[1] / 4;
    const int ngen = in_sizes[15];
    const int* dst = edges;      // node_idx (segment ids)
    const int* src = edges + E;  // nbr_idx (gather source)
    float* out = (float*)d_out;

    const int nblk  = (n + 63) / 64;
    const int npad  = nblk * 64;
    const int nbins = (n + NPB - 1) / NPB;

    // workspace layout (256B aligned slabs)
    char* ws = (char*)d_ws;
    size_t off = 0;
    auto alloc = [&](size_t bytes) -> char* {
        char* p = ws + off;
        off = (off + bytes + 255) & ~(size_t)255;
        return p;
    };
    int* row_start = (int*)alloc((size_t)(n + 1) * 4);
    int* binCnt    = (int*)alloc(256 * 4);
    int* binStart  = (int*)alloc(256 * 4);
    int* snbr      = (int*)alloc((size_t)E * 4);
    half_t* repsA  = (half_t*)alloc((size_t)npad * 32 * 2);
    half_t* repsB  = (half_t*)alloc((size_t)npad * 32 * 2);
    half_t* Wt1    = (half_t*)alloc(32768 * 2);
    half_t* Wt2    = (half_t*)alloc(32768 * 2);
    half_t* Wt3    = (half_t*)alloc(4096 * 2);
    int2* staged   = (int2*)alloc((size_t)nbins * BIN_CAP * 8);   // CSR build only

    // ---- CSR build (binned) + stats + reps ----
    hipMemsetAsync(binCnt, 0, 256 * 4, stream);
    int nblkA = (E + 8191) / 8192;
    k_binA<<<nblkA, 256, 0, stream>>>(dst, src, binCnt, staged, E, nbins);
    k_scanN<<<1, 256, 0, stream>>>(binCnt, binStart, row_start, nbins, n, E);
    k_binB<<<nbins, 512, 0, stream>>>(binCnt, binStart, staged, x, ew,
                                      row_start, snbr, repsA, n);
    k_wprep<<<272, 256, 0, stream>>>(Wu1, Wu2, Wu3, Wt1, Wt2, Wt3);

    half_t* cur = repsA;
    half_t* nxt = repsB;
    for (int it = 0; it < 3; ++it) {
        k_mlp<<<nblk, 512, 0, stream>>>(cur, row_start, snbr, Wt1, Wt2, Wt3,
                                        bu1, bu2, bu3, nxt, n);
        half_t* t = cur; cur = nxt; nxt = t;
    }

    k_readout<<<(ngen + 255) / 256, 256, 0, stream>>>(cur, gen, Wr1, br1, Wr2, br2,
                                                      Wr3, br3, out, ngen);
}